// Round 10
// baseline (355.279 us; speedup 1.0000x reference)
//
#include <hip/hip_runtime.h>
#include <hip/hip_fp16.h>
#include <math.h>

#define NN 50000
#define NE 800000
#define IN_F 20
#define HID 64
#define HEADS 4
#define HD 64
#define CH 32      // hidden//2
#define C1 32      // classifier hidden
#define OUTC 2

// per-block exclusive scan (256 elems); block sums out
__global__ void k_scan_block(const int* __restrict__ in, int* __restrict__ out,
                             int* __restrict__ bsum, int n){
  __shared__ int tmp[256];
  int g = blockIdx.x * 256 + threadIdx.x;
  int v = (g < n) ? in[g] : 0;
  tmp[threadIdx.x] = v;
  __syncthreads();
  for (int o = 1; o < 256; o <<= 1) {
    int t = ((int)threadIdx.x >= o) ? tmp[threadIdx.x - o] : 0;
    __syncthreads();
    tmp[threadIdx.x] += t;
    __syncthreads();
  }
  if (g < n) out[g] = tmp[threadIdx.x] - v;   // exclusive
  if (bsum && threadIdx.x == 255) bsum[blockIdx.x] = tmp[255];
}

__global__ void k_add_off(int* __restrict__ rowptr, const int* __restrict__ bsum_ex, int n){
  int g = blockIdx.x * 256 + threadIdx.x;
  if (g < n) rowptr[g] += bsum_ex[g >> 8];
}

// DESTRUCTIVE scatter: p = rowptr[d]++; afterwards rowptr[n] = END of node n,
// so downstream uses r1 = rowptr[n], r0 = (n ? rowptr[n-1] : 0).
__global__ void k_scatter(const int* __restrict__ src, const int* __restrict__ dst,
                          int* __restrict__ rowptrM, unsigned* __restrict__ colu){
  int e = blockIdx.x * 256 + threadIdx.x;
  if (e >= NE) return;
  int d = dst[e];
  int p = atomicAdd(&rowptrM[d], 1);
  colu[p] = (unsigned)src[e] | ((unsigned)d << 16);
}

// fused prep: in-degree count; xh = fp16(x); was/wad folded att vectors; W2r reorder
__global__ void k_prep(const float* __restrict__ x, const float* __restrict__ W2,
                       const float* __restrict__ att_src, const float* __restrict__ att_dst,
                       const int* __restrict__ dst,
                       __half* __restrict__ xh, float* __restrict__ was,
                       float* __restrict__ wad, float* __restrict__ W2r,
                       int* __restrict__ count){
  int i = blockIdx.x * 256 + threadIdx.x;
  if (i < NN * IN_F) xh[i] = __float2half(x[i]);
  if (i < NE) atomicAdd(&count[dst[i]], 1);
  if (i < 256 * 64) {
    int hk = i >> 6, d = i & 63;
    int h = hk >> 6, k = hk & 63;
    W2r[i] = W2[k * 256 + h * 64 + d];
  }
  if (i < 256) {
    int h = i >> 6, k = i & 63;
    float s = 0.f, dd = 0.f;
    for (int d = 0; d < 64; d++) {
      float w = W2[k * 256 + h * 64 + d];
      s  += w * att_src[h * 64 + d];
      dd += w * att_dst[h * 64 + d];
    }
    was[i] = s; wad[i] = dd;
  }
}

// FUSED aggx-gather + sage1 + attention logits: wave per node.
// Gather agg(x) into lanes, then 20x64 matmul via shfl broadcasts + LDS weights.
__global__ void __launch_bounds__(256) k_sage1f(
    const int* __restrict__ rowptrM, const unsigned* __restrict__ colu,
    const float* __restrict__ x, const __half* __restrict__ xh,
    const int* __restrict__ count,
    const float* __restrict__ Wl, const float* __restrict__ Wr,
    const float* __restrict__ b, const float* __restrict__ g,
    const float* __restrict__ bt,
    const float* __restrict__ was, const float* __restrict__ wad,
    __half* __restrict__ h1h, float* __restrict__ a_s, float* __restrict__ a_d){
  __shared__ float sWl[IN_F * HID], sWr[IN_F * HID], sWas[256], sWad[256];
  for (int i = threadIdx.x; i < IN_F * HID; i += 256) { sWl[i] = Wl[i]; sWr[i] = Wr[i]; }
  { int i = threadIdx.x; sWas[i] = was[i]; sWad[i] = wad[i]; }
  __syncthreads();
  int wid = threadIdx.x >> 6, lane = threadIdx.x & 63;
  int grp = lane >> 5, f = lane & 31;
  int n = blockIdx.x * 4 + wid;
  if (n >= NN) return;
  int r1 = rowptrM[n];
  int r0 = n ? rowptrM[n - 1] : 0;
  int mid = r0 + ((r1 - r0) >> 1);
  int jlo = grp ? mid : r0;
  int jhi = grp ? r1 : mid;
  int ff = f < IN_F ? f : 0;
  float acc = 0.f;
#define AX4(a,b_,c,d) { \
    float v0 = __half2float(xh[(int)((a)&0xffffu) * IN_F + ff]); \
    float v1 = __half2float(xh[(int)((b_)&0xffffu) * IN_F + ff]); \
    float v2 = __half2float(xh[(int)((c)&0xffffu) * IN_F + ff]); \
    float v3 = __half2float(xh[(int)((d)&0xffffu) * IN_F + ff]); \
    acc += (v0 + v1) + (v2 + v3); }
  int j = jlo;
  if (j + 4 <= jhi) {
    unsigned c0 = colu[j], c1 = colu[j+1], c2 = colu[j+2], c3 = colu[j+3];
    for (j += 4; j + 4 <= jhi; j += 4) {
      unsigned n0 = colu[j], n1 = colu[j+1], n2 = colu[j+2], n3 = colu[j+3];
      AX4(c0, c1, c2, c3);
      c0 = n0; c1 = n1; c2 = n2; c3 = n3;
    }
    AX4(c0, c1, c2, c3);
  }
  for (; j < jhi; j++) acc += __half2float(xh[(int)(colu[j] & 0xffffu) * IN_F + ff]);
#undef AX4
  acc += __shfl_xor(acc, 32);   // all lanes now hold agg[f]
  float inv = 1.f / fmaxf((float)count[n], 1.f);
  float xv = (f < IN_F) ? x[(size_t)n * IN_F + ff] : 0.f;
  // matmul: lane j computes h1[j]
  float h = b[lane];
  #pragma unroll
  for (int k = 0; k < IN_F; k++) {
    float aggk = __shfl(acc, k);
    float xk = __shfl(xv, k);
    h += (aggk * inv) * sWl[k * HID + lane] + xk * sWr[k * HID + lane];
  }
  h = h * (g[lane] * rsqrtf(1.f + 1e-5f)) + bt[lane];
  h = fmaxf(h, 0.f);
  h1h[(size_t)n * HID + lane] = __float2half(h);
  #pragma unroll
  for (int hh = 0; hh < HEADS; hh++) {
    float vs = h * sWas[hh * 64 + lane];
    float vd = h * sWad[hh * 64 + lane];
    #pragma unroll
    for (int o = 32; o > 0; o >>= 1) { vs += __shfl_down(vs, o); vd += __shfl_down(vd, o); }
    if (lane == 0) { a_s[n * 4 + hh] = vs; a_d[n * 4 + hh] = vd; }
  }
}

static __device__ __forceinline__ float4 edge_p(float4 as, float4 ad){
  float e0 = as.x + ad.x; e0 = e0 >= 0.f ? e0 : 0.2f * e0;
  float e1 = as.y + ad.y; e1 = e1 >= 0.f ? e1 : 0.2f * e1;
  float e2 = as.z + ad.z; e2 = e2 >= 0.f ? e2 : 0.2f * e2;
  float e3 = as.w + ad.w; e3 = e3 >= 0.f ? e3 : 0.2f * e3;
  return make_float4(__expf(e0), __expf(e1), __expf(e2), __expf(e3));
}

// Fused GAT: wave per node, contiguous-half edge groups, pipelined colu prefetch.
__global__ void k_gat_fused(const int* __restrict__ rowptrM, const unsigned* __restrict__ colu,
                            const float4* __restrict__ a_s4, const float4* __restrict__ a_d4,
                            const __half* __restrict__ h1h, __half* __restrict__ z){
  int wid = threadIdx.x >> 6;
  int lane = threadIdx.x & 63;
  int grp = lane >> 5;
  int idx = lane & 31;            // feature pair index
  int n = blockIdx.x * 4 + wid;
  if (n >= NN) return;
  int r1 = rowptrM[n];
  int r0 = n ? rowptrM[n - 1] : 0;
  int mid = r0 + ((r1 - r0) >> 1);
  int jlo = grp ? mid : r0;
  int jhi = grp ? r1 : mid;
  float4 ad = a_d4[n];
  float l0 = 0.f, l1 = 0.f, l2 = 0.f, l3 = 0.f;
  float2 ac0 = {0,0}, ac1 = {0,0}, ac2 = {0,0}, ac3 = {0,0};
#define GAT1(cc) { \
    int s = (int)((cc) & 0xffffu); \
    float4 as = a_s4[s]; \
    float2 v = __half22float2(*(const __half2*)(h1h + (size_t)s * 64 + 2 * idx)); \
    float4 p = edge_p(as, ad); \
    l0 += p.x; l1 += p.y; l2 += p.z; l3 += p.w; \
    ac0.x += p.x*v.x; ac0.y += p.x*v.y; \
    ac1.x += p.y*v.x; ac1.y += p.y*v.y; \
    ac2.x += p.z*v.x; ac2.y += p.z*v.y; \
    ac3.x += p.w*v.x; ac3.y += p.w*v.y; }
#define GAT4(q0,q1,q2,q3) { \
    int s0=(int)((q0)&0xffffu), s1=(int)((q1)&0xffffu), s2=(int)((q2)&0xffffu), s3=(int)((q3)&0xffffu); \
    float4 as0 = a_s4[s0], as1 = a_s4[s1], as2 = a_s4[s2], as3 = a_s4[s3]; \
    float2 v0 = __half22float2(*(const __half2*)(h1h + (size_t)s0 * 64 + 2 * idx)); \
    float2 v1 = __half22float2(*(const __half2*)(h1h + (size_t)s1 * 64 + 2 * idx)); \
    float2 v2 = __half22float2(*(const __half2*)(h1h + (size_t)s2 * 64 + 2 * idx)); \
    float2 v3 = __half22float2(*(const __half2*)(h1h + (size_t)s3 * 64 + 2 * idx)); \
    float4 p0 = edge_p(as0, ad), p1 = edge_p(as1, ad); \
    float4 p2 = edge_p(as2, ad), p3 = edge_p(as3, ad); \
    l0 += (p0.x + p1.x) + (p2.x + p3.x); \
    l1 += (p0.y + p1.y) + (p2.y + p3.y); \
    l2 += (p0.z + p1.z) + (p2.z + p3.z); \
    l3 += (p0.w + p1.w) + (p2.w + p3.w); \
    ac0.x += p0.x*v0.x + p1.x*v1.x + p2.x*v2.x + p3.x*v3.x; \
    ac0.y += p0.x*v0.y + p1.x*v1.y + p2.x*v2.y + p3.x*v3.y; \
    ac1.x += p0.y*v0.x + p1.y*v1.x + p2.y*v2.x + p3.y*v3.x; \
    ac1.y += p0.y*v0.y + p1.y*v1.y + p2.y*v2.y + p3.y*v3.y; \
    ac2.x += p0.z*v0.x + p1.z*v1.x + p2.z*v2.x + p3.z*v3.x; \
    ac2.y += p0.z*v0.y + p1.z*v1.y + p2.z*v2.y + p3.z*v3.y; \
    ac3.x += p0.w*v0.x + p1.w*v1.x + p2.w*v2.x + p3.w*v3.x; \
    ac3.y += p0.w*v0.y + p1.w*v1.y + p2.w*v2.y + p3.w*v3.y; }
  int j = jlo;
  if (j + 4 <= jhi) {
    unsigned c0 = colu[j], c1 = colu[j+1], c2 = colu[j+2], c3 = colu[j+3];
    for (j += 4; j + 4 <= jhi; j += 4) {
      unsigned n0 = colu[j], n1 = colu[j+1], n2 = colu[j+2], n3 = colu[j+3];
      GAT4(c0, c1, c2, c3);
      c0 = n0; c1 = n1; c2 = n2; c3 = n3;
    }
    GAT4(c0, c1, c2, c3);
  }
  for (; j < jhi; j++) { unsigned cc = colu[j]; GAT1(cc); }
#undef GAT4
#undef GAT1
  l0 += __shfl_xor(l0, 32); l1 += __shfl_xor(l1, 32);
  l2 += __shfl_xor(l2, 32); l3 += __shfl_xor(l3, 32);
  ac0.x += __shfl_xor(ac0.x, 32); ac0.y += __shfl_xor(ac0.y, 32);
  ac1.x += __shfl_xor(ac1.x, 32); ac1.y += __shfl_xor(ac1.y, 32);
  ac2.x += __shfl_xor(ac2.x, 32); ac2.y += __shfl_xor(ac2.y, 32);
  ac3.x += __shfl_xor(ac3.x, 32); ac3.y += __shfl_xor(ac3.y, 32);
  if (grp == 0) {
    float i0 = 1.f / (4.f * (l0 + 1e-16f));
    float i1 = 1.f / (4.f * (l1 + 1e-16f));
    float i2 = 1.f / (4.f * (l2 + 1e-16f));
    float i3 = 1.f / (4.f * (l3 + 1e-16f));
    __half* zr = z + (size_t)n * 256;
    *(__half2*)(zr +       2 * idx) = __floats2half2_rn(ac0.x * i0, ac0.y * i0);
    *(__half2*)(zr +  64 + 2 * idx) = __floats2half2_rn(ac1.x * i1, ac1.y * i1);
    *(__half2*)(zr + 128 + 2 * idx) = __floats2half2_rn(ac2.x * i2, ac2.y * i2);
    *(__half2*)(zr + 192 + 2 * idx) = __floats2half2_rn(ac3.x * i3, ac3.y * i3);
  }
}

// h2h[n,d] = fp16(relu(bn2( z'[n,:] @ W2r[:,d] + b2[d] )))
__global__ void __launch_bounds__(256) k_zproj(const __half* __restrict__ z,
                      const float* __restrict__ W2r, const float* __restrict__ b2,
                      const float* __restrict__ g2, const float* __restrict__ bt2,
                      __half* __restrict__ h2h){
  __shared__ float sz[4][256];
  __shared__ float sacc[4][4][64];
  int tid = threadIdx.x;
  int w = tid >> 6, d = tid & 63;
  float wreg[64];
  #pragma unroll
  for (int i = 0; i < 64; i++) wreg[i] = W2r[(w * 64 + i) * 64 + d];
  float gd = g2[d] * rsqrtf(1.f + 1e-5f), btd = bt2[d], bd = b2[d];
  int n0base = blockIdx.x * 64;
  for (int r = 0; r < 16; r++) {
    int n0 = n0base + r * 4;
    for (int i = tid; i < 512; i += 256) {
      int m = i >> 7, c = (i & 127) * 2;
      int n = n0 + m;
      if (n < NN) {
        __half2 hv = *(const __half2*)(z + (size_t)n * 256 + c);
        float2 f = __half22float2(hv);
        sz[m][c] = f.x; sz[m][c + 1] = f.y;
      } else { sz[m][c] = 0.f; sz[m][c + 1] = 0.f; }
    }
    __syncthreads();
    #pragma unroll
    for (int m = 0; m < 4; m++) {
      float acc = 0.f;
      #pragma unroll
      for (int i = 0; i < 64; i++) acc += sz[m][w * 64 + i] * wreg[i];
      sacc[m][w][d] = acc;
    }
    __syncthreads();
    int n = n0 + w;
    if (n < NN) {
      float rr = sacc[w][0][d] + sacc[w][1][d] + sacc[w][2][d] + sacc[w][3][d] + bd;
      rr = rr * gd + btd;
      rr = fmaxf(rr, 0.f);
      h2h[(size_t)n * 64 + d] = __float2half(rr);
    }
    __syncthreads();
  }
}

// FUSED agg3 + sage3 + skip + classifier + log_softmax: wave per node; writes out.
__global__ void __launch_bounds__(256) k_sage3c(
    const int* __restrict__ rowptrM, const unsigned* __restrict__ colu,
    const __half* __restrict__ h2h, const int* __restrict__ count,
    const float* __restrict__ x,
    const float* __restrict__ Wl3, const float* __restrict__ Wr3,
    const float* __restrict__ b3, const float* __restrict__ g3,
    const float* __restrict__ bt3,
    const float* __restrict__ Wskip, const float* __restrict__ bskip,
    const float* __restrict__ Wc1, const float* __restrict__ bc1,
    const float* __restrict__ Wc2, const float* __restrict__ bc2,
    float* __restrict__ out){
  __shared__ float sWl[HID * CH], sWr[HID * CH], sWs[IN_F * CH];
  __shared__ float sW1[C1 * C1], sW2[C1 * OUTC];
  __shared__ float sA[4][HID], sH[4][HID];
  for (int i = threadIdx.x; i < HID * CH; i += 256) { sWl[i] = Wl3[i]; sWr[i] = Wr3[i]; }
  for (int i = threadIdx.x; i < IN_F * CH; i += 256) sWs[i] = Wskip[i];
  for (int i = threadIdx.x; i < C1 * C1; i += 256) sW1[i] = Wc1[i];
  if (threadIdx.x < C1 * OUTC) sW2[threadIdx.x] = Wc2[threadIdx.x];
  int wid = threadIdx.x >> 6, lane = threadIdx.x & 63;
  int grp = lane >> 5, idx = lane & 31;
  int n = blockIdx.x * 4 + wid;
  int nc = n < NN ? n : NN - 1;
  int r1 = rowptrM[nc];
  int r0 = nc ? rowptrM[nc - 1] : 0;
  int mid = r0 + ((r1 - r0) >> 1);
  int jlo = grp ? mid : r0;
  int jhi = grp ? r1 : mid;
  float2 av = {0, 0};
#define AGG4(q0,q1,q2,q3) { \
    int s0=(int)((q0)&0xffffu), s1=(int)((q1)&0xffffu), s2=(int)((q2)&0xffffu), s3=(int)((q3)&0xffffu); \
    float2 v0 = __half22float2(*(const __half2*)(h2h + (size_t)s0 * 64 + 2 * idx)); \
    float2 v1 = __half22float2(*(const __half2*)(h2h + (size_t)s1 * 64 + 2 * idx)); \
    float2 v2 = __half22float2(*(const __half2*)(h2h + (size_t)s2 * 64 + 2 * idx)); \
    float2 v3 = __half22float2(*(const __half2*)(h2h + (size_t)s3 * 64 + 2 * idx)); \
    av.x += (v0.x + v1.x) + (v2.x + v3.x); \
    av.y += (v0.y + v1.y) + (v2.y + v3.y); }
  int j = jlo;
  if (j + 4 <= jhi) {
    unsigned c0 = colu[j], c1 = colu[j+1], c2 = colu[j+2], c3 = colu[j+3];
    for (j += 4; j + 4 <= jhi; j += 4) {
      unsigned n0 = colu[j], n1 = colu[j+1], n2 = colu[j+2], n3 = colu[j+3];
      AGG4(c0, c1, c2, c3);
      c0 = n0; c1 = n1; c2 = n2; c3 = n3;
    }
    AGG4(c0, c1, c2, c3);
  }
  for (; j < jhi; j++) {
    float2 v = __half22float2(*(const __half2*)(h2h + (size_t)(colu[j] & 0xffffu) * 64 + 2 * idx));
    av.x += v.x; av.y += v.y;
  }
#undef AGG4
  av.x += __shfl_xor(av.x, 32);
  av.y += __shfl_xor(av.y, 32);
  float inv = 1.f / fmaxf((float)count[nc], 1.f);
  if (grp == 0) { sA[wid][2 * idx] = av.x * inv; sA[wid][2 * idx + 1] = av.y * inv; }
  sH[wid][lane] = __half2float(h2h[(size_t)nc * 64 + lane]);
  __syncthreads();
  int kbase = grp * 32;
  float c0 = 0.f, c1 = 0.f;
  #pragma unroll
  for (int k0 = 0; k0 < 32; k0 += 2) {
    int k = kbase + k0;
    c0 += sA[wid][k] * sWl[k * CH + idx] + sH[wid][k] * sWr[k * CH + idx];
    c1 += sA[wid][k+1] * sWl[(k+1) * CH + idx] + sH[wid][k+1] * sWr[(k+1) * CH + idx];
  }
  float c = c0 + c1;
  c += __shfl_xor(c, 32);   // all lanes now hold pre-bn value for output idx
  // bn3 + relu + skip
  float xv = (idx < IN_F) ? x[(size_t)nc * IN_F + idx] : 0.f;
  float bnv = c + b3[idx];
  bnv = bnv * (g3[idx] * rsqrtf(1.f + 1e-5f)) + bt3[idx];
  bnv = fmaxf(bnv, 0.f);
  float idn = bskip[idx];
  #pragma unroll
  for (int k = 0; k < IN_F; k++) idn += __shfl(xv, k) * sWs[k * CH + idx];
  float hrow = bnv + idn;          // lanes 0..31 hold h-row (lanes 32..63 duplicate)
  // classifier: lane i computes hidden c_i
  float ci = bc1[idx];
  #pragma unroll
  for (int jj = 0; jj < CH; jj++) ci += __shfl(hrow, jj) * sW1[jj * C1 + idx];
  ci = fmaxf(ci, 0.f);
  float p0 = ci * sW2[idx * OUTC + 0];
  float p1 = ci * sW2[idx * OUTC + 1];
  #pragma unroll
  for (int o = 16; o > 0; o >>= 1) { p0 += __shfl_xor(p0, o); p1 += __shfl_xor(p1, o); }
  if (lane == 0 && n < NN) {
    float l0 = p0 + bc2[0], l1 = p1 + bc2[1];
    float mx = fmaxf(l0, l1);
    float lse = mx + logf(expf(l0 - mx) + expf(l1 - mx));
    out[(size_t)n * OUTC + 0] = l0 - lse;
    out[(size_t)n * OUTC + 1] = l1 - lse;
  }
}

extern "C" void kernel_launch(void* const* d_in, const int* in_sizes, int n_in,
                              void* d_out, int out_size, void* d_ws, size_t ws_size,
                              hipStream_t stream) {
  const float* x       = (const float*)d_in[0];
  const int*   ei      = (const int*)d_in[1];
  const float* Wl1     = (const float*)d_in[2];
  const float* Wr1     = (const float*)d_in[3];
  const float* b1      = (const float*)d_in[4];
  const float* g1      = (const float*)d_in[5];
  const float* bt1     = (const float*)d_in[6];
  const float* W2      = (const float*)d_in[7];
  const float* att_src = (const float*)d_in[8];
  const float* att_dst = (const float*)d_in[9];
  const float* b2      = (const float*)d_in[10];
  const float* g2      = (const float*)d_in[11];
  const float* bt2     = (const float*)d_in[12];
  const float* Wl3     = (const float*)d_in[13];
  const float* Wr3     = (const float*)d_in[14];
  const float* b3      = (const float*)d_in[15];
  const float* g3      = (const float*)d_in[16];
  const float* bt3     = (const float*)d_in[17];
  const float* Wskip   = (const float*)d_in[18];
  const float* bskip   = (const float*)d_in[19];
  const float* Wc1     = (const float*)d_in[20];
  const float* bc1     = (const float*)d_in[21];
  const float* Wc2     = (const float*)d_in[22];
  const float* bc2     = (const float*)d_in[23];
  float* out = (float*)d_out;

  const int* src = ei;
  const int* dst = ei + NE;

  float* ws = (float*)d_ws;
  size_t off = 0;
  auto alloc = [&](size_t nf) { size_t o = off; off += (nf + 63) & ~(size_t)63; return o; };
  // zero region: count only — memset'd
  size_t o_count = alloc(NN);
  size_t zero_elems = off;
  size_t o_rowptr = alloc(NN + 1);
  size_t o_bsum   = alloc(256);
  size_t o_bsumex = alloc(256);
  size_t o_colu   = alloc(NE);
  size_t o_xh     = alloc((size_t)NN * IN_F / 2 + 64);      // fp16
  size_t o_h1h    = alloc((size_t)NN * HID / 2 + 64);       // fp16
  size_t o_as     = alloc((size_t)NN * HEADS);
  size_t o_ad     = alloc((size_t)NN * HEADS);
  size_t o_was    = alloc(256);
  size_t o_wad    = alloc(256);
  size_t o_w2r    = alloc(256 * 64);
  size_t o_z      = alloc((size_t)NN * 256 / 2 + 64);       // fp16
  size_t o_h2h    = alloc((size_t)NN * HID / 2 + 64);       // fp16
  (void)ws_size; (void)in_sizes; (void)n_in; (void)out_size;

  int* count     = (int*)(ws + o_count);
  int* rowptr    = (int*)(ws + o_rowptr);
  int* bsum      = (int*)(ws + o_bsum);
  int* bsumex    = (int*)(ws + o_bsumex);
  unsigned* colu = (unsigned*)(ws + o_colu);
  __half* xh     = (__half*)(ws + o_xh);
  __half* h1h    = (__half*)(ws + o_h1h);
  float* a_s     = ws + o_as;
  float* a_d     = ws + o_ad;
  float* was     = ws + o_was;
  float* wad     = ws + o_wad;
  float* W2r     = ws + o_w2r;
  __half* z      = (__half*)(ws + o_z);
  __half* h2h    = (__half*)(ws + o_h2h);

  auto nb = [](long long n) { return (int)((n + 255) / 256); };
  const int nscan = nb(NN);  // 196

  hipMemsetAsync(ws, 0, zero_elems * sizeof(int), stream);
  k_prep<<<nb((long long)NN * IN_F), 256, 0, stream>>>(x, W2, att_src, att_dst, dst,
                                                       xh, was, wad, W2r, count);
  k_scan_block<<<nscan, 256, 0, stream>>>(count, rowptr, bsum, NN);
  k_scan_block<<<1, 256, 0, stream>>>(bsum, bsumex, nullptr, nscan);
  k_add_off<<<nscan, 256, 0, stream>>>(rowptr, bsumex, NN);
  k_scatter<<<nb(NE), 256, 0, stream>>>(src, dst, rowptr, colu);   // destructive rowptr
  k_sage1f<<<(NN + 3) / 4, 256, 0, stream>>>(rowptr, colu, x, xh, count,
                                             Wl1, Wr1, b1, g1, bt1, was, wad,
                                             h1h, a_s, a_d);
  k_gat_fused<<<(NN + 3) / 4, 256, 0, stream>>>(rowptr, colu, (const float4*)a_s,
                                                (const float4*)a_d, h1h, z);
  k_zproj<<<(NN + 63) / 64, 256, 0, stream>>>(z, W2r, b2, g2, bt2, h2h);
  k_sage3c<<<(NN + 3) / 4, 256, 0, stream>>>(rowptr, colu, h2h, count, x,
                                             Wl3, Wr3, b3, g3, bt3,
                                             Wskip, bskip, Wc1, bc1, Wc2, bc2, out);
}

// Round 11
// 320.655 us; speedup vs baseline: 1.1080x; 1.1080x over previous
//
#include <hip/hip_runtime.h>
#include <hip/hip_fp16.h>
#include <math.h>

#define NN 50000
#define NE 800000
#define IN_F 20
#define HID 64
#define HEADS 4
#define HD 64
#define CH 32      // hidden//2
#define C1 32      // classifier hidden
#define OUTC 2

// per-block exclusive scan (256 elems); block sums out
__global__ void k_scan_block(const int* __restrict__ in, int* __restrict__ out,
                             int* __restrict__ bsum, int n){
  __shared__ int tmp[256];
  int g = blockIdx.x * 256 + threadIdx.x;
  int v = (g < n) ? in[g] : 0;
  tmp[threadIdx.x] = v;
  __syncthreads();
  for (int o = 1; o < 256; o <<= 1) {
    int t = ((int)threadIdx.x >= o) ? tmp[threadIdx.x - o] : 0;
    __syncthreads();
    tmp[threadIdx.x] += t;
    __syncthreads();
  }
  if (g < n) out[g] = tmp[threadIdx.x] - v;   // exclusive
  if (bsum && threadIdx.x == 255) bsum[blockIdx.x] = tmp[255];
}

__global__ void k_add_off(int* __restrict__ rowptr, const int* __restrict__ bsum_ex, int n){
  int g = blockIdx.x * 256 + threadIdx.x;
  if (g < n) rowptr[g] += bsum_ex[g >> 8];
}

// DESTRUCTIVE scatter: p = rowptr[d]++; afterwards rowptr[n] = END of node n,
// so downstream uses r1 = rowptr[n], r0 = (n ? rowptr[n-1] : 0), deg = r1-r0.
__global__ void k_scatter(const int* __restrict__ src, const int* __restrict__ dst,
                          int* __restrict__ rowptrM, unsigned* __restrict__ colu){
  int e = blockIdx.x * 256 + threadIdx.x;
  if (e >= NE) return;
  int d = dst[e];
  int p = atomicAdd(&rowptrM[d], 1);
  colu[p] = (unsigned)src[e] | ((unsigned)d << 16);
}

// fused prep: in-degree count; xh = fp16(x); was/wad folded att vectors; W2r reorder
__global__ void k_prep(const float* __restrict__ x, const float* __restrict__ W2,
                       const float* __restrict__ att_src, const float* __restrict__ att_dst,
                       const int* __restrict__ dst,
                       __half* __restrict__ xh, float* __restrict__ was,
                       float* __restrict__ wad, float* __restrict__ W2r,
                       int* __restrict__ count){
  int i = blockIdx.x * 256 + threadIdx.x;
  if (i < NN * IN_F) xh[i] = __float2half(x[i]);
  if (i < NE) atomicAdd(&count[dst[i]], 1);
  if (i < 256 * 64) {
    int hk = i >> 6, d = i & 63;
    int h = hk >> 6, k = hk & 63;
    W2r[i] = W2[k * 256 + h * 64 + d];
  }
  if (i < 256) {
    int h = i >> 6, k = i & 63;
    float s = 0.f, dd = 0.f;
    for (int d = 0; d < 64; d++) {
      float w = W2[k * 256 + h * 64 + d];
      s  += w * att_src[h * 64 + d];
      dd += w * att_dst[h * 64 + d];
    }
    was[i] = s; wad[i] = dd;
  }
}

// FUSED aggx-gather + sage1 + attention logits: wave per node.
__global__ void __launch_bounds__(256) k_sage1f(
    const int* __restrict__ rowptrM, const unsigned* __restrict__ colu,
    const float* __restrict__ x, const __half* __restrict__ xh,
    const float* __restrict__ Wl, const float* __restrict__ Wr,
    const float* __restrict__ b, const float* __restrict__ g,
    const float* __restrict__ bt,
    const float* __restrict__ was, const float* __restrict__ wad,
    __half* __restrict__ h1h, float* __restrict__ a_s, float* __restrict__ a_d){
  __shared__ float sWl[IN_F * HID], sWr[IN_F * HID], sWas[256], sWad[256];
  for (int i = threadIdx.x; i < IN_F * HID; i += 256) { sWl[i] = Wl[i]; sWr[i] = Wr[i]; }
  { int i = threadIdx.x; sWas[i] = was[i]; sWad[i] = wad[i]; }
  __syncthreads();
  int wid = threadIdx.x >> 6, lane = threadIdx.x & 63;
  int grp = lane >> 5, f = lane & 31;
  int n = blockIdx.x * 4 + wid;
  if (n >= NN) return;
  int r1 = rowptrM[n];
  int r0 = n ? rowptrM[n - 1] : 0;
  int mid = r0 + ((r1 - r0) >> 1);
  int jlo = grp ? mid : r0;
  int jhi = grp ? r1 : mid;
  int ff = f < IN_F ? f : 0;
  float acc = 0.f;
#define AX4(a,b_,c,d) { \
    float v0 = __half2float(xh[(int)((a)&0xffffu) * IN_F + ff]); \
    float v1 = __half2float(xh[(int)((b_)&0xffffu) * IN_F + ff]); \
    float v2 = __half2float(xh[(int)((c)&0xffffu) * IN_F + ff]); \
    float v3 = __half2float(xh[(int)((d)&0xffffu) * IN_F + ff]); \
    acc += (v0 + v1) + (v2 + v3); }
  int j = jlo;
  if (j + 4 <= jhi) {
    unsigned c0 = colu[j], c1 = colu[j+1], c2 = colu[j+2], c3 = colu[j+3];
    for (j += 4; j + 4 <= jhi; j += 4) {
      unsigned n0 = colu[j], n1 = colu[j+1], n2 = colu[j+2], n3 = colu[j+3];
      AX4(c0, c1, c2, c3);
      c0 = n0; c1 = n1; c2 = n2; c3 = n3;
    }
    AX4(c0, c1, c2, c3);
  }
  for (; j < jhi; j++) acc += __half2float(xh[(int)(colu[j] & 0xffffu) * IN_F + ff]);
#undef AX4
  acc += __shfl_xor(acc, 32);   // all lanes now hold agg[f]
  float inv = 1.f / fmaxf((float)(r1 - r0), 1.f);
  float xv = (f < IN_F) ? x[(size_t)n * IN_F + ff] : 0.f;
  float h = b[lane];
  #pragma unroll
  for (int k = 0; k < IN_F; k++) {
    float aggk = __shfl(acc, k);
    float xk = __shfl(xv, k);
    h += (aggk * inv) * sWl[k * HID + lane] + xk * sWr[k * HID + lane];
  }
  h = h * (g[lane] * rsqrtf(1.f + 1e-5f)) + bt[lane];
  h = fmaxf(h, 0.f);
  h1h[(size_t)n * HID + lane] = __float2half(h);
  #pragma unroll
  for (int hh = 0; hh < HEADS; hh++) {
    float vs = h * sWas[hh * 64 + lane];
    float vd = h * sWad[hh * 64 + lane];
    #pragma unroll
    for (int o = 32; o > 0; o >>= 1) { vs += __shfl_down(vs, o); vd += __shfl_down(vd, o); }
    if (lane == 0) { a_s[n * 4 + hh] = vs; a_d[n * 4 + hh] = vd; }
  }
}

static __device__ __forceinline__ float4 edge_p(float4 as, float4 ad){
  float e0 = as.x + ad.x; e0 = e0 >= 0.f ? e0 : 0.2f * e0;
  float e1 = as.y + ad.y; e1 = e1 >= 0.f ? e1 : 0.2f * e1;
  float e2 = as.z + ad.z; e2 = e2 >= 0.f ? e2 : 0.2f * e2;
  float e3 = as.w + ad.w; e3 = e3 >= 0.f ? e3 : 0.2f * e3;
  return make_float4(__expf(e0), __expf(e1), __expf(e2), __expf(e3));
}

// Fused GAT: wave per node, contiguous-half edge groups, pipelined colu prefetch.
__global__ void k_gat_fused(const int* __restrict__ rowptrM, const unsigned* __restrict__ colu,
                            const float4* __restrict__ a_s4, const float4* __restrict__ a_d4,
                            const __half* __restrict__ h1h, __half* __restrict__ z){
  int wid = threadIdx.x >> 6;
  int lane = threadIdx.x & 63;
  int grp = lane >> 5;
  int idx = lane & 31;            // feature pair index
  int n = blockIdx.x * 4 + wid;
  if (n >= NN) return;
  int r1 = rowptrM[n];
  int r0 = n ? rowptrM[n - 1] : 0;
  int mid = r0 + ((r1 - r0) >> 1);
  int jlo = grp ? mid : r0;
  int jhi = grp ? r1 : mid;
  float4 ad = a_d4[n];
  float l0 = 0.f, l1 = 0.f, l2 = 0.f, l3 = 0.f;
  float2 ac0 = {0,0}, ac1 = {0,0}, ac2 = {0,0}, ac3 = {0,0};
#define GAT1(cc) { \
    int s = (int)((cc) & 0xffffu); \
    float4 as = a_s4[s]; \
    float2 v = __half22float2(*(const __half2*)(h1h + (size_t)s * 64 + 2 * idx)); \
    float4 p = edge_p(as, ad); \
    l0 += p.x; l1 += p.y; l2 += p.z; l3 += p.w; \
    ac0.x += p.x*v.x; ac0.y += p.x*v.y; \
    ac1.x += p.y*v.x; ac1.y += p.y*v.y; \
    ac2.x += p.z*v.x; ac2.y += p.z*v.y; \
    ac3.x += p.w*v.x; ac3.y += p.w*v.y; }
#define GAT4(q0,q1,q2,q3) { \
    int s0=(int)((q0)&0xffffu), s1=(int)((q1)&0xffffu), s2=(int)((q2)&0xffffu), s3=(int)((q3)&0xffffu); \
    float4 as0 = a_s4[s0], as1 = a_s4[s1], as2 = a_s4[s2], as3 = a_s4[s3]; \
    float2 v0 = __half22float2(*(const __half2*)(h1h + (size_t)s0 * 64 + 2 * idx)); \
    float2 v1 = __half22float2(*(const __half2*)(h1h + (size_t)s1 * 64 + 2 * idx)); \
    float2 v2 = __half22float2(*(const __half2*)(h1h + (size_t)s2 * 64 + 2 * idx)); \
    float2 v3 = __half22float2(*(const __half2*)(h1h + (size_t)s3 * 64 + 2 * idx)); \
    float4 p0 = edge_p(as0, ad), p1 = edge_p(as1, ad); \
    float4 p2 = edge_p(as2, ad), p3 = edge_p(as3, ad); \
    l0 += (p0.x + p1.x) + (p2.x + p3.x); \
    l1 += (p0.y + p1.y) + (p2.y + p3.y); \
    l2 += (p0.z + p1.z) + (p2.z + p3.z); \
    l3 += (p0.w + p1.w) + (p2.w + p3.w); \
    ac0.x += p0.x*v0.x + p1.x*v1.x + p2.x*v2.x + p3.x*v3.x; \
    ac0.y += p0.x*v0.y + p1.x*v1.y + p2.x*v2.y + p3.x*v3.y; \
    ac1.x += p0.y*v0.x + p1.y*v1.x + p2.y*v2.x + p3.y*v3.x; \
    ac1.y += p0.y*v0.y + p1.y*v1.y + p2.y*v2.y + p3.y*v3.y; \
    ac2.x += p0.z*v0.x + p1.z*v1.x + p2.z*v2.x + p3.z*v3.x; \
    ac2.y += p0.z*v0.y + p1.z*v1.y + p2.z*v2.y + p3.z*v3.y; \
    ac3.x += p0.w*v0.x + p1.w*v1.x + p2.w*v2.x + p3.w*v3.x; \
    ac3.y += p0.w*v0.y + p1.w*v1.y + p2.w*v2.y + p3.w*v3.y; }
  int j = jlo;
  if (j + 4 <= jhi) {
    unsigned c0 = colu[j], c1 = colu[j+1], c2 = colu[j+2], c3 = colu[j+3];
    for (j += 4; j + 4 <= jhi; j += 4) {
      unsigned n0 = colu[j], n1 = colu[j+1], n2 = colu[j+2], n3 = colu[j+3];
      GAT4(c0, c1, c2, c3);
      c0 = n0; c1 = n1; c2 = n2; c3 = n3;
    }
    GAT4(c0, c1, c2, c3);
  }
  for (; j < jhi; j++) { unsigned cc = colu[j]; GAT1(cc); }
#undef GAT4
#undef GAT1
  l0 += __shfl_xor(l0, 32); l1 += __shfl_xor(l1, 32);
  l2 += __shfl_xor(l2, 32); l3 += __shfl_xor(l3, 32);
  ac0.x += __shfl_xor(ac0.x, 32); ac0.y += __shfl_xor(ac0.y, 32);
  ac1.x += __shfl_xor(ac1.x, 32); ac1.y += __shfl_xor(ac1.y, 32);
  ac2.x += __shfl_xor(ac2.x, 32); ac2.y += __shfl_xor(ac2.y, 32);
  ac3.x += __shfl_xor(ac3.x, 32); ac3.y += __shfl_xor(ac3.y, 32);
  if (grp == 0) {
    float i0 = 1.f / (4.f * (l0 + 1e-16f));
    float i1 = 1.f / (4.f * (l1 + 1e-16f));
    float i2 = 1.f / (4.f * (l2 + 1e-16f));
    float i3 = 1.f / (4.f * (l3 + 1e-16f));
    __half* zr = z + (size_t)n * 256;
    *(__half2*)(zr +       2 * idx) = __floats2half2_rn(ac0.x * i0, ac0.y * i0);
    *(__half2*)(zr +  64 + 2 * idx) = __floats2half2_rn(ac1.x * i1, ac1.y * i1);
    *(__half2*)(zr + 128 + 2 * idx) = __floats2half2_rn(ac2.x * i2, ac2.y * i2);
    *(__half2*)(zr + 192 + 2 * idx) = __floats2half2_rn(ac3.x * i3, ac3.y * i3);
  }
}

// h2h[n,d] = fp16(relu(bn2( z'[n,:] @ W2r[:,d] + b2[d] )))
__global__ void __launch_bounds__(256) k_zproj(const __half* __restrict__ z,
                      const float* __restrict__ W2r, const float* __restrict__ b2,
                      const float* __restrict__ g2, const float* __restrict__ bt2,
                      __half* __restrict__ h2h){
  __shared__ float sz[4][256];
  __shared__ float sacc[4][4][64];
  int tid = threadIdx.x;
  int w = tid >> 6, d = tid & 63;
  float wreg[64];
  #pragma unroll
  for (int i = 0; i < 64; i++) wreg[i] = W2r[(w * 64 + i) * 64 + d];
  float gd = g2[d] * rsqrtf(1.f + 1e-5f), btd = bt2[d], bd = b2[d];
  int n0base = blockIdx.x * 64;
  for (int r = 0; r < 16; r++) {
    int n0 = n0base + r * 4;
    for (int i = tid; i < 512; i += 256) {
      int m = i >> 7, c = (i & 127) * 2;
      int n = n0 + m;
      if (n < NN) {
        __half2 hv = *(const __half2*)(z + (size_t)n * 256 + c);
        float2 f = __half22float2(hv);
        sz[m][c] = f.x; sz[m][c + 1] = f.y;
      } else { sz[m][c] = 0.f; sz[m][c + 1] = 0.f; }
    }
    __syncthreads();
    #pragma unroll
    for (int m = 0; m < 4; m++) {
      float acc = 0.f;
      #pragma unroll
      for (int i = 0; i < 64; i++) acc += sz[m][w * 64 + i] * wreg[i];
      sacc[m][w][d] = acc;
    }
    __syncthreads();
    int n = n0 + w;
    if (n < NN) {
      float rr = sacc[w][0][d] + sacc[w][1][d] + sacc[w][2][d] + sacc[w][3][d] + bd;
      rr = rr * gd + btd;
      rr = fmaxf(rr, 0.f);
      h2h[(size_t)n * 64 + d] = __float2half(rr);
    }
    __syncthreads();
  }
}

// FUSED agg3 + sage3 (separate cls — R10's in-wave cls tail serialized and lost 45us):
// wave per node, contiguous-half groups, pipelined colu prefetch; root from fp16 h2h.
__global__ void __launch_bounds__(256) k_sage3f(
    const int* __restrict__ rowptrM, const unsigned* __restrict__ colu,
    const __half* __restrict__ h2h,
    const float* __restrict__ Wl3, const float* __restrict__ Wr3,
    const float* __restrict__ b3, const float* __restrict__ g3,
    const float* __restrict__ bt3, float* __restrict__ h3){
  __shared__ float sWl[HID * CH], sWr[HID * CH];
  __shared__ float sA[4][HID], sH[4][HID];
  for (int i = threadIdx.x; i < HID * CH; i += 256) { sWl[i] = Wl3[i]; sWr[i] = Wr3[i]; }
  int wid = threadIdx.x >> 6, lane = threadIdx.x & 63;
  int grp = lane >> 5, idx = lane & 31;
  int n = blockIdx.x * 4 + wid;
  int nc = n < NN ? n : NN - 1;
  int r1 = rowptrM[nc];
  int r0 = nc ? rowptrM[nc - 1] : 0;
  int mid = r0 + ((r1 - r0) >> 1);
  int jlo = grp ? mid : r0;
  int jhi = grp ? r1 : mid;
  float2 av = {0, 0};
#define AGG4(q0,q1,q2,q3) { \
    int s0=(int)((q0)&0xffffu), s1=(int)((q1)&0xffffu), s2=(int)((q2)&0xffffu), s3=(int)((q3)&0xffffu); \
    float2 v0 = __half22float2(*(const __half2*)(h2h + (size_t)s0 * 64 + 2 * idx)); \
    float2 v1 = __half22float2(*(const __half2*)(h2h + (size_t)s1 * 64 + 2 * idx)); \
    float2 v2 = __half22float2(*(const __half2*)(h2h + (size_t)s2 * 64 + 2 * idx)); \
    float2 v3 = __half22float2(*(const __half2*)(h2h + (size_t)s3 * 64 + 2 * idx)); \
    av.x += (v0.x + v1.x) + (v2.x + v3.x); \
    av.y += (v0.y + v1.y) + (v2.y + v3.y); }
  int j = jlo;
  if (j + 4 <= jhi) {
    unsigned c0 = colu[j], c1 = colu[j+1], c2 = colu[j+2], c3 = colu[j+3];
    for (j += 4; j + 4 <= jhi; j += 4) {
      unsigned n0 = colu[j], n1 = colu[j+1], n2 = colu[j+2], n3 = colu[j+3];
      AGG4(c0, c1, c2, c3);
      c0 = n0; c1 = n1; c2 = n2; c3 = n3;
    }
    AGG4(c0, c1, c2, c3);
  }
  for (; j < jhi; j++) {
    float2 v = __half22float2(*(const __half2*)(h2h + (size_t)(colu[j] & 0xffffu) * 64 + 2 * idx));
    av.x += v.x; av.y += v.y;
  }
#undef AGG4
  av.x += __shfl_xor(av.x, 32);
  av.y += __shfl_xor(av.y, 32);
  float inv = 1.f / fmaxf((float)(r1 - r0), 1.f);
  if (grp == 0) { sA[wid][2 * idx] = av.x * inv; sA[wid][2 * idx + 1] = av.y * inv; }
  sH[wid][lane] = __half2float(h2h[(size_t)nc * 64 + lane]);
  __syncthreads();
  int kbase = grp * 32;
  float c0 = 0.f, c1 = 0.f;
  #pragma unroll
  for (int k0 = 0; k0 < 32; k0 += 2) {
    int k = kbase + k0;
    c0 += sA[wid][k] * sWl[k * CH + idx] + sH[wid][k] * sWr[k * CH + idx];
    c1 += sA[wid][k+1] * sWl[(k+1) * CH + idx] + sH[wid][k+1] * sWr[(k+1) * CH + idx];
  }
  float c = c0 + c1;
  c += __shfl_xor(c, 32);
  if (grp == 0 && n < NN) {
    float acc = c + b3[idx];
    acc = acc * (g3[idx] * rsqrtf(1.f + 1e-5f)) + bt3[idx];
    h3[(size_t)n * CH + idx] = fmaxf(acc, 0.f);
  }
}

// classifier (+ skip connection x@Wskip+bskip): 256-thread blocks, LDS h3 tile.
__global__ void __launch_bounds__(256) k_cls(const float* __restrict__ h3,
                      const float* __restrict__ x,
                      const float* __restrict__ Wskip, const float* __restrict__ bskip,
                      const float* __restrict__ Wc1, const float* __restrict__ bc1,
                      const float* __restrict__ Wc2, const float* __restrict__ bc2,
                      float* __restrict__ out){
  __shared__ float sW1[C1 * C1], sW2[C1 * OUTC], sb1[C1], sb2[OUTC];
  __shared__ float sWs[IN_F * CH], sbsk[CH];
  __shared__ float sh3[256][CH + 1];
  int tid = threadIdx.x;
  int n0 = blockIdx.x * 256;
  for (int i = tid; i < C1 * C1; i += 256) sW1[i] = Wc1[i];
  for (int i = tid; i < IN_F * CH; i += 256) sWs[i] = Wskip[i];
  if (tid < C1 * OUTC) sW2[tid] = Wc2[tid];
  if (tid < C1) { sb1[tid] = bc1[tid]; sbsk[tid] = bskip[tid]; }
  if (tid < OUTC) sb2[tid] = bc2[tid];
  for (int i = tid; i < 256 * CH; i += 256) {
    int m = i >> 5, c = i & 31;
    int n = n0 + m;
    sh3[m][c] = (n < NN) ? h3[(size_t)n * CH + c] : 0.f;
  }
  __syncthreads();
  int n = n0 + tid;
  if (n >= NN) return;
  float xr[IN_F];
  #pragma unroll
  for (int k = 0; k < IN_F; k++) xr[k] = x[(size_t)n * IN_F + k];
  float hrow[CH];
  #pragma unroll
  for (int j = 0; j < CH; j++) {
    float idn = sbsk[j];
    #pragma unroll
    for (int k = 0; k < IN_F; k++) idn += xr[k] * sWs[k * CH + j];
    hrow[j] = sh3[tid][j] + idn;
  }
  float l0 = sb2[0], l1 = sb2[1];
  #pragma unroll
  for (int i = 0; i < C1; i++) {
    float c0 = sb1[i], c1 = 0.f;
    #pragma unroll
    for (int j = 0; j < CH; j += 2) {
      c0 += hrow[j] * sW1[j * C1 + i];
      c1 += hrow[j + 1] * sW1[(j + 1) * C1 + i];
    }
    float c = fmaxf(c0 + c1, 0.f);
    l0 += c * sW2[i * OUTC + 0];
    l1 += c * sW2[i * OUTC + 1];
  }
  float mx = fmaxf(l0, l1);
  float lse = mx + logf(expf(l0 - mx) + expf(l1 - mx));
  out[n * OUTC + 0] = l0 - lse;
  out[n * OUTC + 1] = l1 - lse;
}

extern "C" void kernel_launch(void* const* d_in, const int* in_sizes, int n_in,
                              void* d_out, int out_size, void* d_ws, size_t ws_size,
                              hipStream_t stream) {
  const float* x       = (const float*)d_in[0];
  const int*   ei      = (const int*)d_in[1];
  const float* Wl1     = (const float*)d_in[2];
  const float* Wr1     = (const float*)d_in[3];
  const float* b1      = (const float*)d_in[4];
  const float* g1      = (const float*)d_in[5];
  const float* bt1     = (const float*)d_in[6];
  const float* W2      = (const float*)d_in[7];
  const float* att_src = (const float*)d_in[8];
  const float* att_dst = (const float*)d_in[9];
  const float* b2      = (const float*)d_in[10];
  const float* g2      = (const float*)d_in[11];
  const float* bt2     = (const float*)d_in[12];
  const float* Wl3     = (const float*)d_in[13];
  const float* Wr3     = (const float*)d_in[14];
  const float* b3      = (const float*)d_in[15];
  const float* g3      = (const float*)d_in[16];
  const float* bt3     = (const float*)d_in[17];
  const float* Wskip   = (const float*)d_in[18];
  const float* bskip   = (const float*)d_in[19];
  const float* Wc1     = (const float*)d_in[20];
  const float* bc1     = (const float*)d_in[21];
  const float* Wc2     = (const float*)d_in[22];
  const float* bc2     = (const float*)d_in[23];
  float* out = (float*)d_out;

  const int* src = ei;
  const int* dst = ei + NE;

  float* ws = (float*)d_ws;
  size_t off = 0;
  auto alloc = [&](size_t nf) { size_t o = off; off += (nf + 63) & ~(size_t)63; return o; };
  // zero region: count only — memset'd
  size_t o_count = alloc(NN);
  size_t zero_elems = off;
  size_t o_rowptr = alloc(NN + 1);
  size_t o_bsum   = alloc(256);
  size_t o_bsumex = alloc(256);
  size_t o_colu   = alloc(NE);
  size_t o_xh     = alloc((size_t)NN * IN_F / 2 + 64);      // fp16
  size_t o_h1h    = alloc((size_t)NN * HID / 2 + 64);       // fp16
  size_t o_as     = alloc((size_t)NN * HEADS);
  size_t o_ad     = alloc((size_t)NN * HEADS);
  size_t o_was    = alloc(256);
  size_t o_wad    = alloc(256);
  size_t o_w2r    = alloc(256 * 64);
  size_t o_z      = alloc((size_t)NN * 256 / 2 + 64);       // fp16
  size_t o_h2h    = alloc((size_t)NN * HID / 2 + 64);       // fp16
  size_t o_h3     = alloc((size_t)NN * CH);
  (void)ws_size; (void)in_sizes; (void)n_in; (void)out_size;

  int* count     = (int*)(ws + o_count);
  int* rowptr    = (int*)(ws + o_rowptr);
  int* bsum      = (int*)(ws + o_bsum);
  int* bsumex    = (int*)(ws + o_bsumex);
  unsigned* colu = (unsigned*)(ws + o_colu);
  __half* xh     = (__half*)(ws + o_xh);
  __half* h1h    = (__half*)(ws + o_h1h);
  float* a_s     = ws + o_as;
  float* a_d     = ws + o_ad;
  float* was     = ws + o_was;
  float* wad     = ws + o_wad;
  float* W2r     = ws + o_w2r;
  __half* z      = (__half*)(ws + o_z);
  __half* h2h    = (__half*)(ws + o_h2h);
  float* h3      = ws + o_h3;

  auto nb = [](long long n) { return (int)((n + 255) / 256); };
  const int nscan = nb(NN);  // 196

  hipMemsetAsync(ws, 0, zero_elems * sizeof(int), stream);
  k_prep<<<nb((long long)NN * IN_F), 256, 0, stream>>>(x, W2, att_src, att_dst, dst,
                                                       xh, was, wad, W2r, count);
  k_scan_block<<<nscan, 256, 0, stream>>>(count, rowptr, bsum, NN);
  k_scan_block<<<1, 256, 0, stream>>>(bsum, bsumex, nullptr, nscan);
  k_add_off<<<nscan, 256, 0, stream>>>(rowptr, bsumex, NN);
  k_scatter<<<nb(NE), 256, 0, stream>>>(src, dst, rowptr, colu);   // destructive rowptr
  k_sage1f<<<(NN + 3) / 4, 256, 0, stream>>>(rowptr, colu, x, xh,
                                             Wl1, Wr1, b1, g1, bt1, was, wad,
                                             h1h, a_s, a_d);
  k_gat_fused<<<(NN + 3) / 4, 256, 0, stream>>>(rowptr, colu, (const float4*)a_s,
                                                (const float4*)a_d, h1h, z);
  k_zproj<<<(NN + 63) / 64, 256, 0, stream>>>(z, W2r, b2, g2, bt2, h2h);
  k_sage3f<<<(NN + 3) / 4, 256, 0, stream>>>(rowptr, colu, h2h,
                                             Wl3, Wr3, b3, g3, bt3, h3);
  k_cls<<<(NN + 255) / 256, 256, 0, stream>>>(h3, x, Wskip, bskip, Wc1, bc1, Wc2, bc2, out);
}

// Round 12
// 299.695 us; speedup vs baseline: 1.1855x; 1.0699x over previous
//
#include <hip/hip_runtime.h>
#include <hip/hip_fp16.h>
#include <math.h>

#define NN 50000
#define NE 800000
#define IN_F 20
#define HID 64
#define HEADS 4
#define HD 64
#define CH 32      // hidden//2
#define C1 32      // classifier hidden
#define OUTC 2

// per-block exclusive scan (256 elems); block sums out
__global__ void k_scan_block(const int* __restrict__ in, int* __restrict__ out,
                             int* __restrict__ bsum, int n){
  __shared__ int tmp[256];
  int g = blockIdx.x * 256 + threadIdx.x;
  int v = (g < n) ? in[g] : 0;
  tmp[threadIdx.x] = v;
  __syncthreads();
  for (int o = 1; o < 256; o <<= 1) {
    int t = ((int)threadIdx.x >= o) ? tmp[threadIdx.x - o] : 0;
    __syncthreads();
    tmp[threadIdx.x] += t;
    __syncthreads();
  }
  if (g < n) out[g] = tmp[threadIdx.x] - v;   // exclusive
  if (bsum && threadIdx.x == 255) bsum[blockIdx.x] = tmp[255];
}

__global__ void k_add_off(int* __restrict__ rowptr, const int* __restrict__ bsum_ex, int n){
  int g = blockIdx.x * 256 + threadIdx.x;
  if (g < n) rowptr[g] += bsum_ex[g >> 8];
}

// DESTRUCTIVE scatter: p = rowptr[d]++; afterwards rowptr[n] = END of node n,
// so downstream uses r1 = rowptr[n], r0 = (n ? rowptr[n-1] : 0), deg = r1-r0.
// colu is ushort (src < 2^16); dst is implicit in CSR position.
__global__ void k_scatter(const int* __restrict__ src, const int* __restrict__ dst,
                          int* __restrict__ rowptrM, unsigned short* __restrict__ colu){
  int e = blockIdx.x * 256 + threadIdx.x;
  if (e >= NE) return;
  int d = dst[e];
  int p = atomicAdd(&rowptrM[d], 1);
  colu[p] = (unsigned short)src[e];
}

// fused prep: in-degree count; xh = fp16(x); was/wad folded att vectors; W2r reorder
__global__ void k_prep(const float* __restrict__ x, const float* __restrict__ W2,
                       const float* __restrict__ att_src, const float* __restrict__ att_dst,
                       const int* __restrict__ dst,
                       __half* __restrict__ xh, float* __restrict__ was,
                       float* __restrict__ wad, float* __restrict__ W2r,
                       int* __restrict__ count){
  int i = blockIdx.x * 256 + threadIdx.x;
  if (i < NN * IN_F) xh[i] = __float2half(x[i]);
  if (i < NE) atomicAdd(&count[dst[i]], 1);
  if (i < 256 * 64) {
    int hk = i >> 6, d = i & 63;
    int h = hk >> 6, k = hk & 63;
    W2r[i] = W2[k * 256 + h * 64 + d];
  }
  if (i < 256) {
    int h = i >> 6, k = i & 63;
    float s = 0.f, dd = 0.f;
    for (int d = 0; d < 64; d++) {
      float w = W2[k * 256 + h * 64 + d];
      s  += w * att_src[h * 64 + d];
      dd += w * att_dst[h * 64 + d];
    }
    was[i] = s; wad[i] = dd;
  }
}

// FUSED aggx-gather + sage1 + attention logits: wave per node.
// Matmul via wave-private LDS handoff (broadcast ds_read), NOT shfl chains
// (R11: 40 serial ds_permutes made this 72us; sage3f's LDS pattern is the fast one).
__global__ void __launch_bounds__(256) k_sage1f(
    const int* __restrict__ rowptrM, const unsigned short* __restrict__ colu,
    const float* __restrict__ x, const __half* __restrict__ xh,
    const float* __restrict__ Wl, const float* __restrict__ Wr,
    const float* __restrict__ b, const float* __restrict__ g,
    const float* __restrict__ bt,
    const float* __restrict__ was, const float* __restrict__ wad,
    __half* __restrict__ h1h, float* __restrict__ a_s, float* __restrict__ a_d){
  __shared__ float sWl[IN_F * HID], sWr[IN_F * HID], sWas[256], sWad[256];
  __shared__ float sAgg[4][IN_F], sX[4][IN_F];
  for (int i = threadIdx.x; i < IN_F * HID; i += 256) { sWl[i] = Wl[i]; sWr[i] = Wr[i]; }
  { int i = threadIdx.x; sWas[i] = was[i]; sWad[i] = wad[i]; }
  __syncthreads();
  int wid = threadIdx.x >> 6, lane = threadIdx.x & 63;
  int grp = lane >> 5, f = lane & 31;
  int n = blockIdx.x * 4 + wid;
  if (n >= NN) return;
  int r1 = rowptrM[n];
  int r0 = n ? rowptrM[n - 1] : 0;
  int mid = r0 + ((r1 - r0) >> 1);
  int jlo = grp ? mid : r0;
  int jhi = grp ? r1 : mid;
  int ff = f < IN_F ? f : 0;
  float acc = 0.f;
#define AX4(a,b_,c,d) { \
    float v0 = __half2float(xh[(int)(a) * IN_F + ff]); \
    float v1 = __half2float(xh[(int)(b_) * IN_F + ff]); \
    float v2 = __half2float(xh[(int)(c) * IN_F + ff]); \
    float v3 = __half2float(xh[(int)(d) * IN_F + ff]); \
    acc += (v0 + v1) + (v2 + v3); }
  int j = jlo;
  if (j + 4 <= jhi) {
    unsigned short c0 = colu[j], c1 = colu[j+1], c2 = colu[j+2], c3 = colu[j+3];
    for (j += 4; j + 4 <= jhi; j += 4) {
      unsigned short n0 = colu[j], n1 = colu[j+1], n2 = colu[j+2], n3 = colu[j+3];
      AX4(c0, c1, c2, c3);
      c0 = n0; c1 = n1; c2 = n2; c3 = n3;
    }
    AX4(c0, c1, c2, c3);
  }
  for (; j < jhi; j++) acc += __half2float(xh[(int)colu[j] * IN_F + ff]);
#undef AX4
  acc += __shfl_xor(acc, 32);   // combine edge halves; lanes 0..19 hold agg[f]
  float inv = 1.f / fmaxf((float)(r1 - r0), 1.f);
  if (lane < IN_F) {
    sAgg[wid][lane] = acc * inv;
    sX[wid][lane] = x[(size_t)n * IN_F + lane];
  }
  // wave-private LDS handoff: no barrier needed (in-wave lgkmcnt ordering)
  float h = b[lane];
  #pragma unroll
  for (int k = 0; k < IN_F; k++)
    h += sAgg[wid][k] * sWl[k * HID + lane] + sX[wid][k] * sWr[k * HID + lane];
  h = h * (g[lane] * rsqrtf(1.f + 1e-5f)) + bt[lane];
  h = fmaxf(h, 0.f);
  h1h[(size_t)n * HID + lane] = __float2half(h);
  #pragma unroll
  for (int hh = 0; hh < HEADS; hh++) {
    float vs = h * sWas[hh * 64 + lane];
    float vd = h * sWad[hh * 64 + lane];
    #pragma unroll
    for (int o = 32; o > 0; o >>= 1) { vs += __shfl_down(vs, o); vd += __shfl_down(vd, o); }
    if (lane == 0) { a_s[n * 4 + hh] = vs; a_d[n * 4 + hh] = vd; }
  }
}

static __device__ __forceinline__ float4 edge_p(float4 as, float4 ad){
  float e0 = as.x + ad.x; e0 = e0 >= 0.f ? e0 : 0.2f * e0;
  float e1 = as.y + ad.y; e1 = e1 >= 0.f ? e1 : 0.2f * e1;
  float e2 = as.z + ad.z; e2 = e2 >= 0.f ? e2 : 0.2f * e2;
  float e3 = as.w + ad.w; e3 = e3 >= 0.f ? e3 : 0.2f * e3;
  return make_float4(__expf(e0), __expf(e1), __expf(e2), __expf(e3));
}

// Fused GAT: wave per node, contiguous-half edge groups, pipelined colu prefetch.
__global__ void k_gat_fused(const int* __restrict__ rowptrM,
                            const unsigned short* __restrict__ colu,
                            const float4* __restrict__ a_s4, const float4* __restrict__ a_d4,
                            const __half* __restrict__ h1h, __half* __restrict__ z){
  int wid = threadIdx.x >> 6;
  int lane = threadIdx.x & 63;
  int grp = lane >> 5;
  int idx = lane & 31;            // feature pair index
  int n = blockIdx.x * 4 + wid;
  if (n >= NN) return;
  int r1 = rowptrM[n];
  int r0 = n ? rowptrM[n - 1] : 0;
  int mid = r0 + ((r1 - r0) >> 1);
  int jlo = grp ? mid : r0;
  int jhi = grp ? r1 : mid;
  float4 ad = a_d4[n];
  float l0 = 0.f, l1 = 0.f, l2 = 0.f, l3 = 0.f;
  float2 ac0 = {0,0}, ac1 = {0,0}, ac2 = {0,0}, ac3 = {0,0};
#define GAT1(cc) { \
    int s = (int)(cc); \
    float4 as = a_s4[s]; \
    float2 v = __half22float2(*(const __half2*)(h1h + (size_t)s * 64 + 2 * idx)); \
    float4 p = edge_p(as, ad); \
    l0 += p.x; l1 += p.y; l2 += p.z; l3 += p.w; \
    ac0.x += p.x*v.x; ac0.y += p.x*v.y; \
    ac1.x += p.y*v.x; ac1.y += p.y*v.y; \
    ac2.x += p.z*v.x; ac2.y += p.z*v.y; \
    ac3.x += p.w*v.x; ac3.y += p.w*v.y; }
#define GAT4(q0,q1,q2,q3) { \
    int s0=(int)(q0), s1=(int)(q1), s2=(int)(q2), s3=(int)(q3); \
    float4 as0 = a_s4[s0], as1 = a_s4[s1], as2 = a_s4[s2], as3 = a_s4[s3]; \
    float2 v0 = __half22float2(*(const __half2*)(h1h + (size_t)s0 * 64 + 2 * idx)); \
    float2 v1 = __half22float2(*(const __half2*)(h1h + (size_t)s1 * 64 + 2 * idx)); \
    float2 v2 = __half22float2(*(const __half2*)(h1h + (size_t)s2 * 64 + 2 * idx)); \
    float2 v3 = __half22float2(*(const __half2*)(h1h + (size_t)s3 * 64 + 2 * idx)); \
    float4 p0 = edge_p(as0, ad), p1 = edge_p(as1, ad); \
    float4 p2 = edge_p(as2, ad), p3 = edge_p(as3, ad); \
    l0 += (p0.x + p1.x) + (p2.x + p3.x); \
    l1 += (p0.y + p1.y) + (p2.y + p3.y); \
    l2 += (p0.z + p1.z) + (p2.z + p3.z); \
    l3 += (p0.w + p1.w) + (p2.w + p3.w); \
    ac0.x += p0.x*v0.x + p1.x*v1.x + p2.x*v2.x + p3.x*v3.x; \
    ac0.y += p0.x*v0.y + p1.x*v1.y + p2.x*v2.y + p3.x*v3.y; \
    ac1.x += p0.y*v0.x + p1.y*v1.x + p2.y*v2.x + p3.y*v3.x; \
    ac1.y += p0.y*v0.y + p1.y*v1.y + p2.y*v2.y + p3.y*v3.y; \
    ac2.x += p0.z*v0.x + p1.z*v1.x + p2.z*v2.x + p3.z*v3.x; \
    ac2.y += p0.z*v0.y + p1.z*v1.y + p2.z*v2.y + p3.z*v3.y; \
    ac3.x += p0.w*v0.x + p1.w*v1.x + p2.w*v2.x + p3.w*v3.x; \
    ac3.y += p0.w*v0.y + p1.w*v1.y + p2.w*v2.y + p3.w*v3.y; }
  int j = jlo;
  if (j + 4 <= jhi) {
    unsigned short c0 = colu[j], c1 = colu[j+1], c2 = colu[j+2], c3 = colu[j+3];
    for (j += 4; j + 4 <= jhi; j += 4) {
      unsigned short n0 = colu[j], n1 = colu[j+1], n2 = colu[j+2], n3 = colu[j+3];
      GAT4(c0, c1, c2, c3);
      c0 = n0; c1 = n1; c2 = n2; c3 = n3;
    }
    GAT4(c0, c1, c2, c3);
  }
  for (; j < jhi; j++) { unsigned short cc = colu[j]; GAT1(cc); }
#undef GAT4
#undef GAT1
  l0 += __shfl_xor(l0, 32); l1 += __shfl_xor(l1, 32);
  l2 += __shfl_xor(l2, 32); l3 += __shfl_xor(l3, 32);
  ac0.x += __shfl_xor(ac0.x, 32); ac0.y += __shfl_xor(ac0.y, 32);
  ac1.x += __shfl_xor(ac1.x, 32); ac1.y += __shfl_xor(ac1.y, 32);
  ac2.x += __shfl_xor(ac2.x, 32); ac2.y += __shfl_xor(ac2.y, 32);
  ac3.x += __shfl_xor(ac3.x, 32); ac3.y += __shfl_xor(ac3.y, 32);
  if (grp == 0) {
    float i0 = 1.f / (4.f * (l0 + 1e-16f));
    float i1 = 1.f / (4.f * (l1 + 1e-16f));
    float i2 = 1.f / (4.f * (l2 + 1e-16f));
    float i3 = 1.f / (4.f * (l3 + 1e-16f));
    __half* zr = z + (size_t)n * 256;
    *(__half2*)(zr +       2 * idx) = __floats2half2_rn(ac0.x * i0, ac0.y * i0);
    *(__half2*)(zr +  64 + 2 * idx) = __floats2half2_rn(ac1.x * i1, ac1.y * i1);
    *(__half2*)(zr + 128 + 2 * idx) = __floats2half2_rn(ac2.x * i2, ac2.y * i2);
    *(__half2*)(zr + 192 + 2 * idx) = __floats2half2_rn(ac3.x * i3, ac3.y * i3);
  }
}

// h2h[n,d] = fp16(relu(bn2( z'[n,:] @ W2r[:,d] + b2[d] )))
__global__ void __launch_bounds__(256) k_zproj(const __half* __restrict__ z,
                      const float* __restrict__ W2r, const float* __restrict__ b2,
                      const float* __restrict__ g2, const float* __restrict__ bt2,
                      __half* __restrict__ h2h){
  __shared__ float sz[4][256];
  __shared__ float sacc[4][4][64];
  int tid = threadIdx.x;
  int w = tid >> 6, d = tid & 63;
  float wreg[64];
  #pragma unroll
  for (int i = 0; i < 64; i++) wreg[i] = W2r[(w * 64 + i) * 64 + d];
  float gd = g2[d] * rsqrtf(1.f + 1e-5f), btd = bt2[d], bd = b2[d];
  int n0base = blockIdx.x * 64;
  for (int r = 0; r < 16; r++) {
    int n0 = n0base + r * 4;
    for (int i = tid; i < 512; i += 256) {
      int m = i >> 7, c = (i & 127) * 2;
      int n = n0 + m;
      if (n < NN) {
        __half2 hv = *(const __half2*)(z + (size_t)n * 256 + c);
        float2 f = __half22float2(hv);
        sz[m][c] = f.x; sz[m][c + 1] = f.y;
      } else { sz[m][c] = 0.f; sz[m][c + 1] = 0.f; }
    }
    __syncthreads();
    #pragma unroll
    for (int m = 0; m < 4; m++) {
      float acc = 0.f;
      #pragma unroll
      for (int i = 0; i < 64; i++) acc += sz[m][w * 64 + i] * wreg[i];
      sacc[m][w][d] = acc;
    }
    __syncthreads();
    int n = n0 + w;
    if (n < NN) {
      float rr = sacc[w][0][d] + sacc[w][1][d] + sacc[w][2][d] + sacc[w][3][d] + bd;
      rr = rr * gd + btd;
      rr = fmaxf(rr, 0.f);
      h2h[(size_t)n * 64 + d] = __float2half(rr);
    }
    __syncthreads();
  }
}

// FUSED agg3 + sage3: wave per node; single barrier (weights only) — sA/sH are
// wave-private so the per-node handoff needs no inter-wave sync.
__global__ void __launch_bounds__(256) k_sage3f(
    const int* __restrict__ rowptrM, const unsigned short* __restrict__ colu,
    const __half* __restrict__ h2h,
    const float* __restrict__ Wl3, const float* __restrict__ Wr3,
    const float* __restrict__ b3, const float* __restrict__ g3,
    const float* __restrict__ bt3, float* __restrict__ h3){
  __shared__ float sWl[HID * CH], sWr[HID * CH];
  __shared__ float sA[4][HID], sH[4][HID];
  for (int i = threadIdx.x; i < HID * CH; i += 256) { sWl[i] = Wl3[i]; sWr[i] = Wr3[i]; }
  __syncthreads();   // weights only
  int wid = threadIdx.x >> 6, lane = threadIdx.x & 63;
  int grp = lane >> 5, idx = lane & 31;
  int n = blockIdx.x * 4 + wid;
  if (n >= NN) return;
  int r1 = rowptrM[n];
  int r0 = n ? rowptrM[n - 1] : 0;
  int mid = r0 + ((r1 - r0) >> 1);
  int jlo = grp ? mid : r0;
  int jhi = grp ? r1 : mid;
  float2 av = {0, 0};
#define AGG4(q0,q1,q2,q3) { \
    int s0=(int)(q0), s1=(int)(q1), s2=(int)(q2), s3=(int)(q3); \
    float2 v0 = __half22float2(*(const __half2*)(h2h + (size_t)s0 * 64 + 2 * idx)); \
    float2 v1 = __half22float2(*(const __half2*)(h2h + (size_t)s1 * 64 + 2 * idx)); \
    float2 v2 = __half22float2(*(const __half2*)(h2h + (size_t)s2 * 64 + 2 * idx)); \
    float2 v3 = __half22float2(*(const __half2*)(h2h + (size_t)s3 * 64 + 2 * idx)); \
    av.x += (v0.x + v1.x) + (v2.x + v3.x); \
    av.y += (v0.y + v1.y) + (v2.y + v3.y); }
  int j = jlo;
  if (j + 4 <= jhi) {
    unsigned short c0 = colu[j], c1 = colu[j+1], c2 = colu[j+2], c3 = colu[j+3];
    for (j += 4; j + 4 <= jhi; j += 4) {
      unsigned short n0 = colu[j], n1 = colu[j+1], n2 = colu[j+2], n3 = colu[j+3];
      AGG4(c0, c1, c2, c3);
      c0 = n0; c1 = n1; c2 = n2; c3 = n3;
    }
    AGG4(c0, c1, c2, c3);
  }
  for (; j < jhi; j++) {
    float2 v = __half22float2(*(const __half2*)(h2h + (size_t)colu[j] * 64 + 2 * idx));
    av.x += v.x; av.y += v.y;
  }
#undef AGG4
  av.x += __shfl_xor(av.x, 32);
  av.y += __shfl_xor(av.y, 32);
  float inv = 1.f / fmaxf((float)(r1 - r0), 1.f);
  if (grp == 0) { sA[wid][2 * idx] = av.x * inv; sA[wid][2 * idx + 1] = av.y * inv; }
  sH[wid][lane] = __half2float(h2h[(size_t)n * 64 + lane]);
  // wave-private handoff: no barrier
  int kbase = grp * 32;
  float c0 = 0.f, c1 = 0.f;
  #pragma unroll
  for (int k0 = 0; k0 < 32; k0 += 2) {
    int k = kbase + k0;
    c0 += sA[wid][k] * sWl[k * CH + idx] + sH[wid][k] * sWr[k * CH + idx];
    c1 += sA[wid][k+1] * sWl[(k+1) * CH + idx] + sH[wid][k+1] * sWr[(k+1) * CH + idx];
  }
  float c = c0 + c1;
  c += __shfl_xor(c, 32);
  if (grp == 0) {
    float acc = c + b3[idx];
    acc = acc * (g3[idx] * rsqrtf(1.f + 1e-5f)) + bt3[idx];
    h3[(size_t)n * CH + idx] = fmaxf(acc, 0.f);
  }
}

// classifier (+ skip connection x@Wskip+bskip): 256-thread blocks, LDS h3 tile.
__global__ void __launch_bounds__(256) k_cls(const float* __restrict__ h3,
                      const float* __restrict__ x,
                      const float* __restrict__ Wskip, const float* __restrict__ bskip,
                      const float* __restrict__ Wc1, const float* __restrict__ bc1,
                      const float* __restrict__ Wc2, const float* __restrict__ bc2,
                      float* __restrict__ out){
  __shared__ float sW1[C1 * C1], sW2[C1 * OUTC], sb1[C1], sb2[OUTC];
  __shared__ float sWs[IN_F * CH], sbsk[CH];
  __shared__ float sh3[256][CH + 1];
  int tid = threadIdx.x;
  int n0 = blockIdx.x * 256;
  for (int i = tid; i < C1 * C1; i += 256) sW1[i] = Wc1[i];
  for (int i = tid; i < IN_F * CH; i += 256) sWs[i] = Wskip[i];
  if (tid < C1 * OUTC) sW2[tid] = Wc2[tid];
  if (tid < C1) { sb1[tid] = bc1[tid]; sbsk[tid] = bskip[tid]; }
  if (tid < OUTC) sb2[tid] = bc2[tid];
  for (int i = tid; i < 256 * CH; i += 256) {
    int m = i >> 5, c = i & 31;
    int n = n0 + m;
    sh3[m][c] = (n < NN) ? h3[(size_t)n * CH + c] : 0.f;
  }
  __syncthreads();
  int n = n0 + tid;
  if (n >= NN) return;
  float xr[IN_F];
  #pragma unroll
  for (int k = 0; k < IN_F; k++) xr[k] = x[(size_t)n * IN_F + k];
  float hrow[CH];
  #pragma unroll
  for (int j = 0; j < CH; j++) {
    float idn = sbsk[j];
    #pragma unroll
    for (int k = 0; k < IN_F; k++) idn += xr[k] * sWs[k * CH + j];
    hrow[j] = sh3[tid][j] + idn;
  }
  float l0 = sb2[0], l1 = sb2[1];
  #pragma unroll
  for (int i = 0; i < C1; i++) {
    float c0 = sb1[i], c1 = 0.f;
    #pragma unroll
    for (int j = 0; j < CH; j += 2) {
      c0 += hrow[j] * sW1[j * C1 + i];
      c1 += hrow[j + 1] * sW1[(j + 1) * C1 + i];
    }
    float c = fmaxf(c0 + c1, 0.f);
    l0 += c * sW2[i * OUTC + 0];
    l1 += c * sW2[i * OUTC + 1];
  }
  float mx = fmaxf(l0, l1);
  float lse = mx + logf(expf(l0 - mx) + expf(l1 - mx));
  out[n * OUTC + 0] = l0 - lse;
  out[n * OUTC + 1] = l1 - lse;
}

extern "C" void kernel_launch(void* const* d_in, const int* in_sizes, int n_in,
                              void* d_out, int out_size, void* d_ws, size_t ws_size,
                              hipStream_t stream) {
  const float* x       = (const float*)d_in[0];
  const int*   ei      = (const int*)d_in[1];
  const float* Wl1     = (const float*)d_in[2];
  const float* Wr1     = (const float*)d_in[3];
  const float* b1      = (const float*)d_in[4];
  const float* g1      = (const float*)d_in[5];
  const float* bt1     = (const float*)d_in[6];
  const float* W2      = (const float*)d_in[7];
  const float* att_src = (const float*)d_in[8];
  const float* att_dst = (const float*)d_in[9];
  const float* b2      = (const float*)d_in[10];
  const float* g2      = (const float*)d_in[11];
  const float* bt2     = (const float*)d_in[12];
  const float* Wl3     = (const float*)d_in[13];
  const float* Wr3     = (const float*)d_in[14];
  const float* b3      = (const float*)d_in[15];
  const float* g3      = (const float*)d_in[16];
  const float* bt3     = (const float*)d_in[17];
  const float* Wskip   = (const float*)d_in[18];
  const float* bskip   = (const float*)d_in[19];
  const float* Wc1     = (const float*)d_in[20];
  const float* bc1     = (const float*)d_in[21];
  const float* Wc2     = (const float*)d_in[22];
  const float* bc2     = (const float*)d_in[23];
  float* out = (float*)d_out;

  const int* src = ei;
  const int* dst = ei + NE;

  float* ws = (float*)d_ws;
  size_t off = 0;
  auto alloc = [&](size_t nf) { size_t o = off; off += (nf + 63) & ~(size_t)63; return o; };
  // zero region: count only — memset'd
  size_t o_count = alloc(NN);
  size_t zero_elems = off;
  size_t o_rowptr = alloc(NN + 1);
  size_t o_bsum   = alloc(256);
  size_t o_bsumex = alloc(256);
  size_t o_colu   = alloc(NE / 2 + 64);                     // ushort
  size_t o_xh     = alloc((size_t)NN * IN_F / 2 + 64);      // fp16
  size_t o_h1h    = alloc((size_t)NN * HID / 2 + 64);       // fp16
  size_t o_as     = alloc((size_t)NN * HEADS);
  size_t o_ad     = alloc((size_t)NN * HEADS);
  size_t o_was    = alloc(256);
  size_t o_wad    = alloc(256);
  size_t o_w2r    = alloc(256 * 64);
  size_t o_z      = alloc((size_t)NN * 256 / 2 + 64);       // fp16
  size_t o_h2h    = alloc((size_t)NN * HID / 2 + 64);       // fp16
  size_t o_h3     = alloc((size_t)NN * CH);
  (void)ws_size; (void)in_sizes; (void)n_in; (void)out_size;

  int* count     = (int*)(ws + o_count);
  int* rowptr    = (int*)(ws + o_rowptr);
  int* bsum      = (int*)(ws + o_bsum);
  int* bsumex    = (int*)(ws + o_bsumex);
  unsigned short* colu = (unsigned short*)(ws + o_colu);
  __half* xh     = (__half*)(ws + o_xh);
  __half* h1h    = (__half*)(ws + o_h1h);
  float* a_s     = ws + o_as;
  float* a_d     = ws + o_ad;
  float* was     = ws + o_was;
  float* wad     = ws + o_wad;
  float* W2r     = ws + o_w2r;
  __half* z      = (__half*)(ws + o_z);
  __half* h2h    = (__half*)(ws + o_h2h);
  float* h3      = ws + o_h3;

  auto nb = [](long long n) { return (int)((n + 255) / 256); };
  const int nscan = nb(NN);  // 196

  hipMemsetAsync(ws, 0, zero_elems * sizeof(int), stream);
  k_prep<<<nb((long long)NN * IN_F), 256, 0, stream>>>(x, W2, att_src, att_dst, dst,
                                                       xh, was, wad, W2r, count);
  k_scan_block<<<nscan, 256, 0, stream>>>(count, rowptr, bsum, NN);
  k_scan_block<<<1, 256, 0, stream>>>(bsum, bsumex, nullptr, nscan);
  k_add_off<<<nscan, 256, 0, stream>>>(rowptr, bsumex, NN);
  k_scatter<<<nb(NE), 256, 0, stream>>>(src, dst, rowptr, colu);   // destructive rowptr
  k_sage1f<<<(NN + 3) / 4, 256, 0, stream>>>(rowptr, colu, x, xh,
                                             Wl1, Wr1, b1, g1, bt1, was, wad,
                                             h1h, a_s, a_d);
  k_gat_fused<<<(NN + 3) / 4, 256, 0, stream>>>(rowptr, colu, (const float4*)a_s,
                                                (const float4*)a_d, h1h, z);
  k_zproj<<<(NN + 63) / 64, 256, 0, stream>>>(z, W2r, b2, g2, bt2, h2h);
  k_sage3f<<<(NN + 3) / 4, 256, 0, stream>>>(rowptr, colu, h2h,
                                             Wl3, Wr3, b3, g3, bt3, h3);
  k_cls<<<(NN + 255) / 256, 256, 0, stream>>>(h3, x, Wskip, bskip, Wc1, bc1, Wc2, bc2, out);
}

// Round 13
// 286.263 us; speedup vs baseline: 1.2411x; 1.0469x over previous
//
#include <hip/hip_runtime.h>
#include <hip/hip_fp16.h>
#include <math.h>

#define NN 50000
#define NE 800000
#define IN_F 20
#define HID 64
#define HEADS 4
#define HD 64
#define CH 32      // hidden//2
#define C1 32      // classifier hidden
#define OUTC 2

// per-block exclusive scan (256 elems); block sums out
__global__ void k_scan_block(const int* __restrict__ in, int* __restrict__ out,
                             int* __restrict__ bsum, int n){
  __shared__ int tmp[256];
  int g = blockIdx.x * 256 + threadIdx.x;
  int v = (g < n) ? in[g] : 0;
  tmp[threadIdx.x] = v;
  __syncthreads();
  for (int o = 1; o < 256; o <<= 1) {
    int t = ((int)threadIdx.x >= o) ? tmp[threadIdx.x - o] : 0;
    __syncthreads();
    tmp[threadIdx.x] += t;
    __syncthreads();
  }
  if (g < n) out[g] = tmp[threadIdx.x] - v;   // exclusive
  if (bsum && threadIdx.x == 255) bsum[blockIdx.x] = tmp[255];
}

__global__ void k_add_off(int* __restrict__ rowptr, const int* __restrict__ bsum_ex, int n){
  int g = blockIdx.x * 256 + threadIdx.x;
  if (g < n) rowptr[g] += bsum_ex[g >> 8];
}

// DESTRUCTIVE scatter: p = rowptr[d]++; afterwards rowptr[n] = END of node n,
// so downstream uses r1 = rowptr[n], r0 = (n ? rowptr[n-1] : 0), deg = r1-r0.
__global__ void k_scatter(const int* __restrict__ src, const int* __restrict__ dst,
                          int* __restrict__ rowptrM, unsigned short* __restrict__ colu){
  int e = blockIdx.x * 256 + threadIdx.x;
  if (e >= NE) return;
  int d = dst[e];
  int p = atomicAdd(&rowptrM[d], 1);
  colu[p] = (unsigned short)src[e];
}

// fused prep: in-degree count; xh = fp16(x); was/wad folded att vectors; W2r reorder
__global__ void k_prep(const float* __restrict__ x, const float* __restrict__ W2,
                       const float* __restrict__ att_src, const float* __restrict__ att_dst,
                       const int* __restrict__ dst,
                       __half* __restrict__ xh, float* __restrict__ was,
                       float* __restrict__ wad, float* __restrict__ W2r,
                       int* __restrict__ count){
  int i = blockIdx.x * 256 + threadIdx.x;
  if (i < NN * IN_F) xh[i] = __float2half(x[i]);
  if (i < NE) atomicAdd(&count[dst[i]], 1);
  if (i < 256 * 64) {
    int hk = i >> 6, d = i & 63;
    int h = hk >> 6, k = hk & 63;
    W2r[i] = W2[k * 256 + h * 64 + d];
  }
  if (i < 256) {
    int h = i >> 6, k = i & 63;
    float s = 0.f, dd = 0.f;
    for (int d = 0; d < 64; d++) {
      float w = W2[k * 256 + h * 64 + d];
      s  += w * att_src[h * 64 + d];
      dd += w * att_dst[h * 64 + d];
    }
    was[i] = s; wad[i] = dd;
  }
}

// FUSED aggx-gather + sage1: wave per node; matmul via wave-private LDS handoff.
// Attention-logit tail moved to k_att (24-deep shfl chain was 13us of sage1f).
__global__ void __launch_bounds__(256) k_sage1f(
    const int* __restrict__ rowptrM, const unsigned short* __restrict__ colu,
    const float* __restrict__ x, const __half* __restrict__ xh,
    const float* __restrict__ Wl, const float* __restrict__ Wr,
    const float* __restrict__ b, const float* __restrict__ g,
    const float* __restrict__ bt, __half* __restrict__ h1h){
  __shared__ float sWl[IN_F * HID], sWr[IN_F * HID];
  __shared__ float sAgg[4][IN_F], sX[4][IN_F];
  for (int i = threadIdx.x; i < IN_F * HID; i += 256) { sWl[i] = Wl[i]; sWr[i] = Wr[i]; }
  __syncthreads();
  int wid = threadIdx.x >> 6, lane = threadIdx.x & 63;
  int grp = lane >> 5, f = lane & 31;
  int n = blockIdx.x * 4 + wid;
  if (n >= NN) return;
  int r1 = rowptrM[n];
  int r0 = n ? rowptrM[n - 1] : 0;
  int mid = r0 + ((r1 - r0) >> 1);
  int jlo = grp ? mid : r0;
  int jhi = grp ? r1 : mid;
  int ff = f < IN_F ? f : 0;
  float acc = 0.f;
#define AX4(a,b_,c,d) { \
    float v0 = __half2float(xh[(int)(a) * IN_F + ff]); \
    float v1 = __half2float(xh[(int)(b_) * IN_F + ff]); \
    float v2 = __half2float(xh[(int)(c) * IN_F + ff]); \
    float v3 = __half2float(xh[(int)(d) * IN_F + ff]); \
    acc += (v0 + v1) + (v2 + v3); }
  int j = jlo;
  if (j + 4 <= jhi) {
    unsigned short c0 = colu[j], c1 = colu[j+1], c2 = colu[j+2], c3 = colu[j+3];
    for (j += 4; j + 4 <= jhi; j += 4) {
      unsigned short n0 = colu[j], n1 = colu[j+1], n2 = colu[j+2], n3 = colu[j+3];
      AX4(c0, c1, c2, c3);
      c0 = n0; c1 = n1; c2 = n2; c3 = n3;
    }
    AX4(c0, c1, c2, c3);
  }
  for (; j < jhi; j++) acc += __half2float(xh[(int)colu[j] * IN_F + ff]);
#undef AX4
  acc += __shfl_xor(acc, 32);   // combine edge halves; lanes 0..19 hold agg[f]
  float inv = 1.f / fmaxf((float)(r1 - r0), 1.f);
  if (lane < IN_F) {
    sAgg[wid][lane] = acc * inv;
    sX[wid][lane] = x[(size_t)n * IN_F + lane];
  }
  // wave-private LDS handoff: no barrier needed (in-wave lgkmcnt ordering)
  float h = b[lane];
  #pragma unroll
  for (int k = 0; k < IN_F; k++)
    h += sAgg[wid][k] * sWl[k * HID + lane] + sX[wid][k] * sWr[k * HID + lane];
  h = h * (g[lane] * rsqrtf(1.f + 1e-5f)) + bt[lane];
  h = fmaxf(h, 0.f);
  h1h[(size_t)n * HID + lane] = __float2half(h);
}

// attention logits: a_s[n][h] = h1h[n,:]·was[h,:], a_d likewise. Thread per node.
__global__ void __launch_bounds__(256) k_att(const __half* __restrict__ h1h,
                      const float* __restrict__ was, const float* __restrict__ wad,
                      float4* __restrict__ a_s4, float4* __restrict__ a_d4){
  __shared__ float sWas[256], sWad[256];
  int tid = threadIdx.x;
  sWas[tid] = was[tid]; sWad[tid] = wad[tid];
  __syncthreads();
  int n = blockIdx.x * 256 + tid;
  if (n >= NN) return;
  const __half* hr = h1h + (size_t)n * 64;
  float s0=0,s1=0,s2=0,s3=0,d0=0,d1=0,d2=0,d3=0;
  #pragma unroll
  for (int k = 0; k < 64; k += 2) {
    float2 hv = __half22float2(*(const __half2*)(hr + k));
    s0 += hv.x * sWas[k]       + hv.y * sWas[k + 1];
    s1 += hv.x * sWas[64 + k]  + hv.y * sWas[64 + k + 1];
    s2 += hv.x * sWas[128 + k] + hv.y * sWas[128 + k + 1];
    s3 += hv.x * sWas[192 + k] + hv.y * sWas[192 + k + 1];
    d0 += hv.x * sWad[k]       + hv.y * sWad[k + 1];
    d1 += hv.x * sWad[64 + k]  + hv.y * sWad[64 + k + 1];
    d2 += hv.x * sWad[128 + k] + hv.y * sWad[128 + k + 1];
    d3 += hv.x * sWad[192 + k] + hv.y * sWad[192 + k + 1];
  }
  a_s4[n] = make_float4(s0, s1, s2, s3);
  a_d4[n] = make_float4(d0, d1, d2, d3);
}

static __device__ __forceinline__ float4 edge_p(float4 as, float4 ad){
  float e0 = as.x + ad.x; e0 = e0 >= 0.f ? e0 : 0.2f * e0;
  float e1 = as.y + ad.y; e1 = e1 >= 0.f ? e1 : 0.2f * e1;
  float e2 = as.z + ad.z; e2 = e2 >= 0.f ? e2 : 0.2f * e2;
  float e3 = as.w + ad.w; e3 = e3 >= 0.f ? e3 : 0.2f * e3;
  return make_float4(__expf(e0), __expf(e1), __expf(e2), __expf(e3));
}

// Fused GAT: wave per node, contiguous-half edge groups, pipelined colu prefetch.
__global__ void k_gat_fused(const int* __restrict__ rowptrM,
                            const unsigned short* __restrict__ colu,
                            const float4* __restrict__ a_s4, const float4* __restrict__ a_d4,
                            const __half* __restrict__ h1h, __half* __restrict__ z){
  int wid = threadIdx.x >> 6;
  int lane = threadIdx.x & 63;
  int grp = lane >> 5;
  int idx = lane & 31;            // feature pair index
  int n = blockIdx.x * 4 + wid;
  if (n >= NN) return;
  int r1 = rowptrM[n];
  int r0 = n ? rowptrM[n - 1] : 0;
  int mid = r0 + ((r1 - r0) >> 1);
  int jlo = grp ? mid : r0;
  int jhi = grp ? r1 : mid;
  float4 ad = a_d4[n];
  float l0 = 0.f, l1 = 0.f, l2 = 0.f, l3 = 0.f;
  float2 ac0 = {0,0}, ac1 = {0,0}, ac2 = {0,0}, ac3 = {0,0};
#define GAT1(cc) { \
    int s = (int)(cc); \
    float4 as = a_s4[s]; \
    float2 v = __half22float2(*(const __half2*)(h1h + (size_t)s * 64 + 2 * idx)); \
    float4 p = edge_p(as, ad); \
    l0 += p.x; l1 += p.y; l2 += p.z; l3 += p.w; \
    ac0.x += p.x*v.x; ac0.y += p.x*v.y; \
    ac1.x += p.y*v.x; ac1.y += p.y*v.y; \
    ac2.x += p.z*v.x; ac2.y += p.z*v.y; \
    ac3.x += p.w*v.x; ac3.y += p.w*v.y; }
#define GAT4(q0,q1,q2,q3) { \
    int s0=(int)(q0), s1=(int)(q1), s2=(int)(q2), s3=(int)(q3); \
    float4 as0 = a_s4[s0], as1 = a_s4[s1], as2 = a_s4[s2], as3 = a_s4[s3]; \
    float2 v0 = __half22float2(*(const __half2*)(h1h + (size_t)s0 * 64 + 2 * idx)); \
    float2 v1 = __half22float2(*(const __half2*)(h1h + (size_t)s1 * 64 + 2 * idx)); \
    float2 v2 = __half22float2(*(const __half2*)(h1h + (size_t)s2 * 64 + 2 * idx)); \
    float2 v3 = __half22float2(*(const __half2*)(h1h + (size_t)s3 * 64 + 2 * idx)); \
    float4 p0 = edge_p(as0, ad), p1 = edge_p(as1, ad); \
    float4 p2 = edge_p(as2, ad), p3 = edge_p(as3, ad); \
    l0 += (p0.x + p1.x) + (p2.x + p3.x); \
    l1 += (p0.y + p1.y) + (p2.y + p3.y); \
    l2 += (p0.z + p1.z) + (p2.z + p3.z); \
    l3 += (p0.w + p1.w) + (p2.w + p3.w); \
    ac0.x += p0.x*v0.x + p1.x*v1.x + p2.x*v2.x + p3.x*v3.x; \
    ac0.y += p0.x*v0.y + p1.x*v1.y + p2.x*v2.y + p3.x*v3.y; \
    ac1.x += p0.y*v0.x + p1.y*v1.x + p2.y*v2.x + p3.y*v3.x; \
    ac1.y += p0.y*v0.y + p1.y*v1.y + p2.y*v2.y + p3.y*v3.y; \
    ac2.x += p0.z*v0.x + p1.z*v1.x + p2.z*v2.x + p3.z*v3.x; \
    ac2.y += p0.z*v0.y + p1.z*v1.y + p2.z*v2.y + p3.z*v3.y; \
    ac3.x += p0.w*v0.x + p1.w*v1.x + p2.w*v2.x + p3.w*v3.x; \
    ac3.y += p0.w*v0.y + p1.w*v1.y + p2.w*v2.y + p3.w*v3.y; }
  int j = jlo;
  if (j + 4 <= jhi) {
    unsigned short c0 = colu[j], c1 = colu[j+1], c2 = colu[j+2], c3 = colu[j+3];
    for (j += 4; j + 4 <= jhi; j += 4) {
      unsigned short n0 = colu[j], n1 = colu[j+1], n2 = colu[j+2], n3 = colu[j+3];
      GAT4(c0, c1, c2, c3);
      c0 = n0; c1 = n1; c2 = n2; c3 = n3;
    }
    GAT4(c0, c1, c2, c3);
  }
  for (; j < jhi; j++) { unsigned short cc = colu[j]; GAT1(cc); }
#undef GAT4
#undef GAT1
  l0 += __shfl_xor(l0, 32); l1 += __shfl_xor(l1, 32);
  l2 += __shfl_xor(l2, 32); l3 += __shfl_xor(l3, 32);
  ac0.x += __shfl_xor(ac0.x, 32); ac0.y += __shfl_xor(ac0.y, 32);
  ac1.x += __shfl_xor(ac1.x, 32); ac1.y += __shfl_xor(ac1.y, 32);
  ac2.x += __shfl_xor(ac2.x, 32); ac2.y += __shfl_xor(ac2.y, 32);
  ac3.x += __shfl_xor(ac3.x, 32); ac3.y += __shfl_xor(ac3.y, 32);
  if (grp == 0) {
    float i0 = 1.f / (4.f * (l0 + 1e-16f));
    float i1 = 1.f / (4.f * (l1 + 1e-16f));
    float i2 = 1.f / (4.f * (l2 + 1e-16f));
    float i3 = 1.f / (4.f * (l3 + 1e-16f));
    __half* zr = z + (size_t)n * 256;
    *(__half2*)(zr +       2 * idx) = __floats2half2_rn(ac0.x * i0, ac0.y * i0);
    *(__half2*)(zr +  64 + 2 * idx) = __floats2half2_rn(ac1.x * i1, ac1.y * i1);
    *(__half2*)(zr + 128 + 2 * idx) = __floats2half2_rn(ac2.x * i2, ac2.y * i2);
    *(__half2*)(zr + 192 + 2 * idx) = __floats2half2_rn(ac3.x * i3, ac3.y * i3);
  }
}

// h2h[n,d] = fp16(relu(bn2( z'[n,:] @ W2r[:,d] + b2[d] )))
__global__ void __launch_bounds__(256) k_zproj(const __half* __restrict__ z,
                      const float* __restrict__ W2r, const float* __restrict__ b2,
                      const float* __restrict__ g2, const float* __restrict__ bt2,
                      __half* __restrict__ h2h){
  __shared__ float sz[4][256];
  __shared__ float sacc[4][4][64];
  int tid = threadIdx.x;
  int w = tid >> 6, d = tid & 63;
  float wreg[64];
  #pragma unroll
  for (int i = 0; i < 64; i++) wreg[i] = W2r[(w * 64 + i) * 64 + d];
  float gd = g2[d] * rsqrtf(1.f + 1e-5f), btd = bt2[d], bd = b2[d];
  int n0base = blockIdx.x * 64;
  for (int r = 0; r < 16; r++) {
    int n0 = n0base + r * 4;
    for (int i = tid; i < 512; i += 256) {
      int m = i >> 7, c = (i & 127) * 2;
      int n = n0 + m;
      if (n < NN) {
        __half2 hv = *(const __half2*)(z + (size_t)n * 256 + c);
        float2 f = __half22float2(hv);
        sz[m][c] = f.x; sz[m][c + 1] = f.y;
      } else { sz[m][c] = 0.f; sz[m][c + 1] = 0.f; }
    }
    __syncthreads();
    #pragma unroll
    for (int m = 0; m < 4; m++) {
      float acc = 0.f;
      #pragma unroll
      for (int i = 0; i < 64; i++) acc += sz[m][w * 64 + i] * wreg[i];
      sacc[m][w][d] = acc;
    }
    __syncthreads();
    int n = n0 + w;
    if (n < NN) {
      float rr = sacc[w][0][d] + sacc[w][1][d] + sacc[w][2][d] + sacc[w][3][d] + bd;
      rr = rr * gd + btd;
      rr = fmaxf(rr, 0.f);
      h2h[(size_t)n * 64 + d] = __float2half(rr);
    }
    __syncthreads();
  }
}

// FUSED agg3 + sage3: wave per node; gather uses 4 groups x 16 lanes (lane = 4
// features via 8B load) -> edge-serial depth quartered, 16 loads in flight.
__global__ void __launch_bounds__(256) k_sage3f(
    const int* __restrict__ rowptrM, const unsigned short* __restrict__ colu,
    const __half* __restrict__ h2h,
    const float* __restrict__ Wl3, const float* __restrict__ Wr3,
    const float* __restrict__ b3, const float* __restrict__ g3,
    const float* __restrict__ bt3, float* __restrict__ h3){
  __shared__ float sWl[HID * CH], sWr[HID * CH];
  __shared__ float sA[4][HID], sH[4][HID];
  for (int i = threadIdx.x; i < HID * CH; i += 256) { sWl[i] = Wl3[i]; sWr[i] = Wr3[i]; }
  __syncthreads();   // weights only
  int wid = threadIdx.x >> 6, lane = threadIdx.x & 63;
  int g4 = lane >> 4, f16 = lane & 15;     // gather: 4 edge-groups x 16 lanes
  int grp = lane >> 5, idx = lane & 31;    // matmul: 2 K-halves x 32 outputs
  int n = blockIdx.x * 4 + wid;
  if (n >= NN) return;
  int r1 = rowptrM[n];
  int r0 = n ? rowptrM[n - 1] : 0;
  int q = (r1 - r0) >> 2;
  int jlo = r0 + q * g4;
  int jhi = (g4 == 3) ? r1 : (jlo + q);
  float a0 = 0.f, a1 = 0.f, a2 = 0.f, a3 = 0.f;
#define AGG1(cc) { \
    float2 w = *(const float2*)(h2h + (size_t)(int)(cc) * 64 + 4 * f16); \
    float2 fa = __half22float2(((const __half2*)&w)[0]); \
    float2 fb = __half22float2(((const __half2*)&w)[1]); \
    a0 += fa.x; a1 += fa.y; a2 += fb.x; a3 += fb.y; }
#define AGG4(q0,q1,q2,q3) { AGG1(q0); AGG1(q1); AGG1(q2); AGG1(q3); }
  int j = jlo;
  if (j + 4 <= jhi) {
    unsigned short c0 = colu[j], c1 = colu[j+1], c2 = colu[j+2], c3 = colu[j+3];
    for (j += 4; j + 4 <= jhi; j += 4) {
      unsigned short n0 = colu[j], n1 = colu[j+1], n2 = colu[j+2], n3 = colu[j+3];
      AGG4(c0, c1, c2, c3);
      c0 = n0; c1 = n1; c2 = n2; c3 = n3;
    }
    AGG4(c0, c1, c2, c3);
  }
  for (; j < jhi; j++) { AGG1(colu[j]); }
#undef AGG4
#undef AGG1
  a0 += __shfl_xor(a0, 16); a1 += __shfl_xor(a1, 16);
  a2 += __shfl_xor(a2, 16); a3 += __shfl_xor(a3, 16);
  a0 += __shfl_xor(a0, 32); a1 += __shfl_xor(a1, 32);
  a2 += __shfl_xor(a2, 32); a3 += __shfl_xor(a3, 32);
  float inv = 1.f / fmaxf((float)(r1 - r0), 1.f);
  if (g4 == 0) {
    float* dstp = &sA[wid][4 * f16];
    dstp[0] = a0 * inv; dstp[1] = a1 * inv; dstp[2] = a2 * inv; dstp[3] = a3 * inv;
  }
  sH[wid][lane] = __half2float(h2h[(size_t)n * 64 + lane]);
  // wave-private handoff: no barrier
  int kbase = grp * 32;
  float c0 = 0.f, c1 = 0.f;
  #pragma unroll
  for (int k0 = 0; k0 < 32; k0 += 2) {
    int k = kbase + k0;
    c0 += sA[wid][k] * sWl[k * CH + idx] + sH[wid][k] * sWr[k * CH + idx];
    c1 += sA[wid][k+1] * sWl[(k+1) * CH + idx] + sH[wid][k+1] * sWr[(k+1) * CH + idx];
  }
  float c = c0 + c1;
  c += __shfl_xor(c, 32);
  if (grp == 0) {
    float acc = c + b3[idx];
    acc = acc * (g3[idx] * rsqrtf(1.f + 1e-5f)) + bt3[idx];
    h3[(size_t)n * CH + idx] = fmaxf(acc, 0.f);
  }
}

// classifier (+ skip connection x@Wskip+bskip): 256-thread blocks, LDS h3 tile.
__global__ void __launch_bounds__(256) k_cls(const float* __restrict__ h3,
                      const float* __restrict__ x,
                      const float* __restrict__ Wskip, const float* __restrict__ bskip,
                      const float* __restrict__ Wc1, const float* __restrict__ bc1,
                      const float* __restrict__ Wc2, const float* __restrict__ bc2,
                      float* __restrict__ out){
  __shared__ float sW1[C1 * C1], sW2[C1 * OUTC], sb1[C1], sb2[OUTC];
  __shared__ float sWs[IN_F * CH], sbsk[CH];
  __shared__ float sh3[256][CH + 1];
  int tid = threadIdx.x;
  int n0 = blockIdx.x * 256;
  for (int i = tid; i < C1 * C1; i += 256) sW1[i] = Wc1[i];
  for (int i = tid; i < IN_F * CH; i += 256) sWs[i] = Wskip[i];
  if (tid < C1 * OUTC) sW2[tid] = Wc2[tid];
  if (tid < C1) { sb1[tid] = bc1[tid]; sbsk[tid] = bskip[tid]; }
  if (tid < OUTC) sb2[tid] = bc2[tid];
  for (int i = tid; i < 256 * CH; i += 256) {
    int m = i >> 5, c = i & 31;
    int n = n0 + m;
    sh3[m][c] = (n < NN) ? h3[(size_t)n * CH + c] : 0.f;
  }
  __syncthreads();
  int n = n0 + tid;
  if (n >= NN) return;
  float xr[IN_F];
  #pragma unroll
  for (int k = 0; k < IN_F; k++) xr[k] = x[(size_t)n * IN_F + k];
  float hrow[CH];
  #pragma unroll
  for (int j = 0; j < CH; j++) {
    float idn = sbsk[j];
    #pragma unroll
    for (int k = 0; k < IN_F; k++) idn += xr[k] * sWs[k * CH + j];
    hrow[j] = sh3[tid][j] + idn;
  }
  float l0 = sb2[0], l1 = sb2[1];
  #pragma unroll
  for (int i = 0; i < C1; i++) {
    float c0 = sb1[i], c1 = 0.f;
    #pragma unroll
    for (int j = 0; j < CH; j += 2) {
      c0 += hrow[j] * sW1[j * C1 + i];
      c1 += hrow[j + 1] * sW1[(j + 1) * C1 + i];
    }
    float c = fmaxf(c0 + c1, 0.f);
    l0 += c * sW2[i * OUTC + 0];
    l1 += c * sW2[i * OUTC + 1];
  }
  float mx = fmaxf(l0, l1);
  float lse = mx + logf(expf(l0 - mx) + expf(l1 - mx));
  out[n * OUTC + 0] = l0 - lse;
  out[n * OUTC + 1] = l1 - lse;
}

extern "C" void kernel_launch(void* const* d_in, const int* in_sizes, int n_in,
                              void* d_out, int out_size, void* d_ws, size_t ws_size,
                              hipStream_t stream) {
  const float* x       = (const float*)d_in[0];
  const int*   ei      = (const int*)d_in[1];
  const float* Wl1     = (const float*)d_in[2];
  const float* Wr1     = (const float*)d_in[3];
  const float* b1      = (const float*)d_in[4];
  const float* g1      = (const float*)d_in[5];
  const float* bt1     = (const float*)d_in[6];
  const float* W2      = (const float*)d_in[7];
  const float* att_src = (const float*)d_in[8];
  const float* att_dst = (const float*)d_in[9];
  const float* b2      = (const float*)d_in[10];
  const float* g2      = (const float*)d_in[11];
  const float* bt2     = (const float*)d_in[12];
  const float* Wl3     = (const float*)d_in[13];
  const float* Wr3     = (const float*)d_in[14];
  const float* b3      = (const float*)d_in[15];
  const float* g3      = (const float*)d_in[16];
  const float* bt3     = (const float*)d_in[17];
  const float* Wskip   = (const float*)d_in[18];
  const float* bskip   = (const float*)d_in[19];
  const float* Wc1     = (const float*)d_in[20];
  const float* bc1     = (const float*)d_in[21];
  const float* Wc2     = (const float*)d_in[22];
  const float* bc2     = (const float*)d_in[23];
  float* out = (float*)d_out;

  const int* src = ei;
  const int* dst = ei + NE;

  float* ws = (float*)d_ws;
  size_t off = 0;
  auto alloc = [&](size_t nf) { size_t o = off; off += (nf + 63) & ~(size_t)63; return o; };
  // zero region: count only — memset'd
  size_t o_count = alloc(NN);
  size_t zero_elems = off;
  size_t o_rowptr = alloc(NN + 1);
  size_t o_bsum   = alloc(256);
  size_t o_bsumex = alloc(256);
  size_t o_colu   = alloc(NE / 2 + 64);                     // ushort
  size_t o_xh     = alloc((size_t)NN * IN_F / 2 + 64);      // fp16
  size_t o_h1h    = alloc((size_t)NN * HID / 2 + 64);       // fp16
  size_t o_as     = alloc((size_t)NN * HEADS);
  size_t o_ad     = alloc((size_t)NN * HEADS);
  size_t o_was    = alloc(256);
  size_t o_wad    = alloc(256);
  size_t o_w2r    = alloc(256 * 64);
  size_t o_z      = alloc((size_t)NN * 256 / 2 + 64);       // fp16
  size_t o_h2h    = alloc((size_t)NN * HID / 2 + 64);       // fp16
  size_t o_h3     = alloc((size_t)NN * CH);
  (void)ws_size; (void)in_sizes; (void)n_in; (void)out_size;

  int* count     = (int*)(ws + o_count);
  int* rowptr    = (int*)(ws + o_rowptr);
  int* bsum      = (int*)(ws + o_bsum);
  int* bsumex    = (int*)(ws + o_bsumex);
  unsigned short* colu = (unsigned short*)(ws + o_colu);
  __half* xh     = (__half*)(ws + o_xh);
  __half* h1h    = (__half*)(ws + o_h1h);
  float* a_s     = ws + o_as;
  float* a_d     = ws + o_ad;
  float* was     = ws + o_was;
  float* wad     = ws + o_wad;
  float* W2r     = ws + o_w2r;
  __half* z      = (__half*)(ws + o_z);
  __half* h2h    = (__half*)(ws + o_h2h);
  float* h3      = ws + o_h3;

  auto nb = [](long long n) { return (int)((n + 255) / 256); };
  const int nscan = nb(NN);  // 196

  hipMemsetAsync(ws, 0, zero_elems * sizeof(int), stream);
  k_prep<<<nb((long long)NN * IN_F), 256, 0, stream>>>(x, W2, att_src, att_dst, dst,
                                                       xh, was, wad, W2r, count);
  k_scan_block<<<nscan, 256, 0, stream>>>(count, rowptr, bsum, NN);
  k_scan_block<<<1, 256, 0, stream>>>(bsum, bsumex, nullptr, nscan);
  k_add_off<<<nscan, 256, 0, stream>>>(rowptr, bsumex, NN);
  k_scatter<<<nb(NE), 256, 0, stream>>>(src, dst, rowptr, colu);   // destructive rowptr
  k_sage1f<<<(NN + 3) / 4, 256, 0, stream>>>(rowptr, colu, x, xh,
                                             Wl1, Wr1, b1, g1, bt1, h1h);
  k_att<<<(NN + 255) / 256, 256, 0, stream>>>(h1h, was, wad, (float4*)a_s, (float4*)a_d);
  k_gat_fused<<<(NN + 3) / 4, 256, 0, stream>>>(rowptr, colu, (const float4*)a_s,
                                                (const float4*)a_d, h1h, z);
  k_zproj<<<(NN + 63) / 64, 256, 0, stream>>>(z, W2r, b2, g2, bt2, h2h);
  k_sage3f<<<(NN + 3) / 4, 256, 0, stream>>>(rowptr, colu, h2h,
                                             Wl3, Wr3, b3, g3, bt3, h3);
  k_cls<<<(NN + 255) / 256, 256, 0, stream>>>(h3, x, Wskip, bskip, Wc1, bc1, Wc2, bc2, out);
}